// Round 1
// 267.835 us; speedup vs baseline: 1.0588x; 1.0588x over previous
//
#include <hip/hip_runtime.h>
#include <hip/hip_fp16.h>

// Problem dims
#define BDIM 32
#define NDIM 400
#define TDIM 315
#define TPAD 320
#define DDIM 512
#define HDIM 256
#define NITER 100

// Workspace layout (bytes), tightly packed (~41 MB)
#define OFS_TAB   0u          // tAb bf16 [320][512] = 327680
#define OFS_TB    327680u     // TB f32 [320][256] = 327680
#define OFS_STATS 655360u     // stats[32][2] f32 = 256
#define OFS_WHB   655616u     // Whb bf16 [512][256] = 262144
#define OFS_S     1048576u    // s fp16 [32][400][320] = 8192000
#define OFS_S1B   9240576u    // s1b bf16 [32][400][320] = 8192000
#define OFS_F1    17432576u   // f1b bf16 [32][315][512] = 10321920  (end 27754496)
#define OFS_FB    27754496u   // Fb bf16 [32][400][512] = 13107200  (end 40861696)
// k_sinkhorn scratch overlaps the f1b region (f1b is produced AFTER sinkhorn):
#define OFS_QBAR  OFS_F1            // arrival counters: 32 batches x 64B stride = 2048
#define OFS_QPART (OFS_F1 + 4096u)  // q partials f32 [2][32][8][320] = 655360

typedef __attribute__((ext_vector_type(8))) short bf16x8;
typedef __attribute__((ext_vector_type(4))) float f32x4;

// ---------------- bf16 pack/unpack (RNE) ----------------
__device__ __forceinline__ unsigned rne_hi(float x) {
  unsigned u = __float_as_uint(x);
  u += 0x7fffu + ((u >> 16) & 1u);
  return u & 0xffff0000u;
}
__device__ __forceinline__ unsigned pack2(float lo, float hi) {
  return (rne_hi(lo) >> 16) | rne_hi(hi);
}
__device__ __forceinline__ unsigned short bf1(float x) { return (unsigned short)(rne_hi(x) >> 16); }

// ---------------- DPP wave reduce helpers (VALU pipe, no LDS) ----------------
template <int CTRL, int RMASK>
__device__ __forceinline__ float dppadd(float x) {
  int y = __builtin_amdgcn_update_dpp(0, __float_as_int(x), CTRL, RMASK, 0xf, true);
  return x + __int_as_float(y);
}
template <int CTRL, int RMASK>
__device__ __forceinline__ float dppmax(float x) {
  int y = __builtin_amdgcn_update_dpp(0, __float_as_int(x), CTRL, RMASK, 0xf, true);
  return fmaxf(x, __int_as_float(y));
}

// ---------------- K0: one-shot bf16 packing of F and Wh_top (grid-stride) -------------------
__global__ void k_pack(const float* __restrict__ F, const float* __restrict__ Wh,
                       unsigned short* __restrict__ Fb, unsigned short* __restrict__ Whb) {
  const int NF4 = (BDIM * NDIM * DDIM) / 4;  // 1638400
  const int NW4 = (DDIM * HDIM) / 4;         // 32768 (top half of Wh is the first 512*256)
  int stride = gridDim.x * blockDim.x;
  for (int i = blockIdx.x * blockDim.x + threadIdx.x; i < NF4; i += stride) {
    float4 v = ((const float4*)F)[i];
    ((uint2*)Fb)[i] = make_uint2(pack2(v.x, v.y), pack2(v.z, v.w));
  }
  for (int i = blockIdx.x * blockDim.x + threadIdx.x; i < NW4; i += stride) {
    float4 v = ((const float4*)Wh)[i];
    ((uint2*)Whb)[i] = make_uint2(pack2(v.x, v.y), pack2(v.z, v.w));
  }
}

// ---------------- fp32 GEMM pieces (k_pre only) ----------------
__device__ __forceinline__ void mm_inner(const float* __restrict__ As, const float* __restrict__ Bs,
                                         float acc[4][4], int tm, int tn) {
#pragma unroll
  for (int k = 0; k < 32; ++k) {
    float4 a = *(const float4*)(As + k * 72 + tm * 4);
    float4 b = *(const float4*)(Bs + k * 72 + tn * 4);
    float ar[4] = {a.x, a.y, a.z, a.w};
    float br[4] = {b.x, b.y, b.z, b.w};
#pragma unroll
    for (int i = 0; i < 4; ++i)
#pragma unroll
      for (int j = 0; j < 4; ++j)
        acc[i][j] = fmaf(ar[i], br[j], acc[i][j]);
  }
}

__device__ __forceinline__ void stage_T(float* __restrict__ Xs, const float* __restrict__ X,
                                        int r0, int ld, int k0, int tid, int rmax) {
  int kq = tid & 7;
  int mb = tid >> 3;
#pragma unroll
  for (int p = 0; p < 2; ++p) {
    int mm = mb + 32 * p;
    int row = r0 + mm;
    float4 v = make_float4(0.f, 0.f, 0.f, 0.f);
    if (row < rmax) v = *(const float4*)(X + (size_t)row * ld + k0 + 4 * kq);
    Xs[(4 * kq + 0) * 72 + mm] = v.x;
    Xs[(4 * kq + 1) * 72 + mm] = v.y;
    Xs[(4 * kq + 2) * 72 + mm] = v.z;
    Xs[(4 * kq + 3) * 72 + mm] = v.w;
  }
}

__device__ __forceinline__ void stage_N(float* __restrict__ Ws, const float* __restrict__ W,
                                        int k0, int ld, int n0, int tid, int kmax) {
  int nq = tid & 15;
  int kk = tid >> 4;
#pragma unroll
  for (int p = 0; p < 2; ++p) {
    int k = kk + 16 * p;
    float4 v = make_float4(0.f, 0.f, 0.f, 0.f);
    if (k0 + k < kmax) v = *(const float4*)(W + (size_t)(k0 + k) * ld + n0 + 4 * nq);
    *(float4*)(Ws + k * 72 + 4 * nq) = v;
  }
}

// ---------------- K1: merged tA (z=0, bf16 out) + TB (z=1) ----------------
__global__ void k_pre(const float* __restrict__ text, const float* __restrict__ A,
                      const float* __restrict__ Wh, const float* __restrict__ bh,
                      unsigned short* __restrict__ tAb, float* __restrict__ TB) {
  __shared__ float Xs[32 * 72], Ys[32 * 72];
  int tid = threadIdx.x, tm = tid >> 4, tn = tid & 15;
  if (blockIdx.z == 0) {
    int d0 = blockIdx.x * 64, t0 = blockIdx.y * 64;
    float acc[4][4] = {};
    for (int k0 = 0; k0 < 512; k0 += 32) {
      stage_T(Xs, text, t0, 512, k0, tid, TDIM);
      stage_T(Ys, A, d0, 512, k0, tid, 512);
      __syncthreads();
      mm_inner(Xs, Ys, acc, tm, tn);
      __syncthreads();
    }
#pragma unroll
    for (int i = 0; i < 4; ++i) {
      int t = t0 + tm * 4 + i;  // pad rows (>=315) get zeros (Xs zero-filled)
      *(uint2*)(tAb + (size_t)t * 512 + d0 + tn * 4) =
          make_uint2(pack2(acc[i][0], acc[i][1]), pack2(acc[i][2], acc[i][3]));
    }
  } else {
    if (blockIdx.x >= 4) return;
    int h0 = blockIdx.x * 64, t0 = blockIdx.y * 64;
    const float* Wb = Wh + 512 * 256;
    float acc[4][4] = {};
    for (int k0 = 0; k0 < 512; k0 += 32) {
      stage_T(Xs, text, t0, 512, k0, tid, TDIM);
      stage_N(Ys, Wb, k0, 256, h0, tid, 512);
      __syncthreads();
      mm_inner(Xs, Ys, acc, tm, tn);
      __syncthreads();
    }
#pragma unroll
    for (int i = 0; i < 4; ++i) {
      int t = t0 + tm * 4 + i;
      int h = h0 + tn * 4;
      *(float4*)(TB + (size_t)t * 256 + h) =
          make_float4(acc[i][0] + bh[h], acc[i][1] + bh[h + 1],
                      acc[i][2] + bh[h + 2], acc[i][3] + bh[h + 3]);
    }
  }
}

// ================= MFMA GEMMs: 64x64 tile, 256 thr (4 waves), 16x16x32 bf16 =================
#define LDH 40

// ---------------- K2: s[b][n][t] (fp16 out) + instnorm stats; operands pre-packed bf16 ------
__global__ __launch_bounds__(256) void k_s(const unsigned short* __restrict__ Fb,
                                           const unsigned short* __restrict__ tAb,
                                           __half* __restrict__ s, float* __restrict__ stats) {
  __shared__ unsigned short Abf[64 * LDH];
  __shared__ unsigned short Bbf[64 * LDH];
  __shared__ float red[8];
  const int tid = threadIdx.x, l = tid & 63, wv = tid >> 6;
  const int t0 = blockIdx.x * 64, n0 = blockIdx.y * 64, bz = blockIdx.z;
  const unsigned short* Fbb = Fb + (size_t)bz * NDIM * DDIM;
  __half* sb = s + (size_t)bz * NDIM * TPAD;
  f32x4 acc[4] = {};
  const int m = tid >> 2, kq = (tid & 3) * 8;
  for (int k0 = 0; k0 < 512; k0 += 32) {
    uint4 av = make_uint4(0, 0, 0, 0);
    int n = n0 + m;
    if (n < NDIM) av = *(const uint4*)(Fbb + (size_t)n * DDIM + k0 + kq);
    *(uint4*)(&Abf[m * LDH + kq]) = av;
    uint4 bv = *(const uint4*)(tAb + (size_t)(t0 + m) * DDIM + k0 + kq);
    *(uint4*)(&Bbf[m * LDH + kq]) = bv;
    __syncthreads();
    bf16x8 af = *(const bf16x8*)(&Abf[(wv * 16 + (l & 15)) * LDH + (l >> 4) * 8]);
#pragma unroll
    for (int c = 0; c < 4; ++c) {
      bf16x8 bf_ = *(const bf16x8*)(&Bbf[(c * 16 + (l & 15)) * LDH + (l >> 4) * 8]);
      acc[c] = __builtin_amdgcn_mfma_f32_16x16x32_bf16(af, bf_, acc[c], 0, 0, 0);
    }
    __syncthreads();
  }
  float lsum = 0.f, lsq = 0.f;
#pragma unroll
  for (int c = 0; c < 4; ++c)
#pragma unroll
    for (int r = 0; r < 4; ++r) {
      int n = n0 + wv * 16 + ((l >> 4) << 2) + r;
      int t = t0 + c * 16 + (l & 15);
      if (n < NDIM && t < TDIM) {
        float v = acc[c][r];
        sb[(size_t)n * TPAD + t] = __float2half(v);
        lsum += v;
        lsq = fmaf(v, v, lsq);
      }
    }
#pragma unroll
  for (int mm = 1; mm <= 32; mm <<= 1) {
    lsum += __shfl_xor(lsum, mm, 64);
    lsq += __shfl_xor(lsq, mm, 64);
  }
  if ((tid & 63) == 0) { red[wv * 2] = lsum; red[wv * 2 + 1] = lsq; }
  __syncthreads();
  if (tid == 0) {
    float S = red[0] + red[2] + red[4] + red[6];
    float Q = red[1] + red[3] + red[5] + red[7];
    atomicAdd(&stats[bz * 2], S);
    atomicAdd(&stats[bz * 2 + 1], Q);
  }
}

// ---------------- K3: multi-CU sinkhorn -----------------------------------------------------
// 8 blocks per batch (grid 256 = 1/CU), 320 thr (5 waves), 10 rows/wave, E fp32 in REGISTERS.
// Row norm is block-local; col sums exchanged via agent-scope partial buffers (double-
// buffered disjoint slots -> no RMW, no zeroing) + a monotonic per-batch arrival counter.
// All blocks recompute identical w/residual bits (fixed summation order) so the early-exit
// decision is uniform chip-wide. Math identical to the previous single-block version
// (exp2 instnorm, rcp scalings, TOL 1e-3 on pre-update w, 'fin' extra iter ends on col-norm).
#define SBLK 8
#define SROWS 50
#define SRPW 10

__global__ __launch_bounds__(320, 1) void k_sinkhorn(const __half* __restrict__ sbuf,
                                                     const float* __restrict__ stats,
                                                     const float* __restrict__ gptr,
                                                     const float* __restrict__ bptr,
                                                     unsigned short* __restrict__ s1b,
                                                     float* __restrict__ qpart,
                                                     unsigned* __restrict__ qbar) {
  __shared__ float qpl[5][320];   // per-wave col partials
  __shared__ float qtot[320];     // broadcast of summed col totals
  const int c = blockIdx.x, b = blockIdx.y;
  const int tid = threadIdx.x, wv = tid >> 6, l = tid & 63;
  const __half* S = sbuf + (size_t)b * NDIM * TPAD;
  unsigned short* S1 = s1b + (size_t)b * NDIM * TPAD;
  const float NT = 400.0f * 315.0f;
  const float mean = stats[2 * b] / NT;
  const float var = stats[2 * b + 1] / NT - mean * mean;
  const float inv = rsqrtf(var + 1e-5f);
  const float alpha = gptr[0] * inv;
  const float L2E = 1.4426950408889634f;
  const float a2 = alpha * L2E;
  const float d2 = (bptr[0] - mean * alpha) * L2E;
  const int r0 = c * SROWS + wv * SRPW;
  const float TOL = 1e-3f;
  const float TN_RATIO = 315.0f / 400.0f;
  unsigned* cnt = qbar + b * 16;  // 64B stride per batch

  // ---- prologue: E = exp(instnorm(s)) into registers, fp32, 5 cols/lane x 10 rows ----
  float E0[SRPW], E1[SRPW], E2[SRPW], E3[SRPW], E4[SRPW];
#pragma unroll
  for (int j = 0; j < SRPW; ++j) {
    const __half* row = S + (size_t)(r0 + j) * TPAD;
    E0[j] = __builtin_amdgcn_exp2f(fmaf(__half2float(row[l]), a2, d2));
    E1[j] = __builtin_amdgcn_exp2f(fmaf(__half2float(row[64 + l]), a2, d2));
    E2[j] = __builtin_amdgcn_exp2f(fmaf(__half2float(row[128 + l]), a2, d2));
    E3[j] = __builtin_amdgcn_exp2f(fmaf(__half2float(row[192 + l]), a2, d2));
    E4[j] = (l < 59) ? __builtin_amdgcn_exp2f(fmaf(__half2float(row[256 + l]), a2, d2)) : 0.0f;
  }
  float w0 = 1.0f, w1 = 1.0f, w2 = 1.0f, w3 = 1.0f, w4 = (l < 59) ? 1.0f : 0.0f;
  float aj[SRPW];
#pragma unroll
  for (int j = 0; j < SRPW; ++j) aj[j] = 0.0f;

  bool fin = false;
  unsigned arrivals = 0;
  for (int it = 0; it < NITER; ++it) {
    // ---- row sums p = E . w (registers only) ----
    float p[SRPW];
#pragma unroll
    for (int j = 0; j < SRPW; ++j) {
      float t = E4[j] * w4;
      t = fmaf(E3[j], w3, t);
      t = fmaf(E2[j], w2, t);
      t = fmaf(E1[j], w1, t);
      p[j] = fmaf(E0[j], w0, t);
    }
#pragma unroll
    for (int j = 0; j < SRPW; ++j) p[j] = dppadd<0x111, 0xf>(p[j]);
#pragma unroll
    for (int j = 0; j < SRPW; ++j) p[j] = dppadd<0x112, 0xf>(p[j]);
#pragma unroll
    for (int j = 0; j < SRPW; ++j) p[j] = dppadd<0x114, 0xf>(p[j]);
#pragma unroll
    for (int j = 0; j < SRPW; ++j) p[j] = dppadd<0x118, 0xf>(p[j]);
#pragma unroll
    for (int j = 0; j < SRPW; ++j) p[j] = dppadd<0x142, 0xa>(p[j]);
#pragma unroll
    for (int j = 0; j < SRPW; ++j) p[j] = dppadd<0x143, 0xc>(p[j]);
#pragma unroll
    for (int j = 0; j < SRPW; ++j) {
      float r = __builtin_amdgcn_rcpf(p[j]);
      aj[j] = __int_as_float(__builtin_amdgcn_readlane(__float_as_int(r), 63));
    }
    // ---- local col partials q = E^T . a ----
    float q0 = 0.f, q1 = 0.f, q2 = 0.f, q3 = 0.f, q4 = 0.f;
#pragma unroll
    for (int j = 0; j < SRPW; ++j) {
      q0 = fmaf(E0[j], aj[j], q0);
      q1 = fmaf(E1[j], aj[j], q1);
      q2 = fmaf(E2[j], aj[j], q2);
      q3 = fmaf(E3[j], aj[j], q3);
      q4 = fmaf(E4[j], aj[j], q4);
    }
    qpl[wv][l] = q0;
    qpl[wv][64 + l] = q1;
    qpl[wv][128 + l] = q2;
    qpl[wv][192 + l] = q3;
    qpl[wv][256 + l] = q4;
    __syncthreads();
    const int par = it & 1;
    if (wv == 0) {
      float* qp = qpart + ((size_t)(par * BDIM + b) * SBLK + c) * 320;
#pragma unroll
      for (int k = 0; k < 5; ++k) {
        int t = k * 64 + l;
        float sm = qpl[0][t] + qpl[1][t] + qpl[2][t] + qpl[3][t] + qpl[4][t];
        __hip_atomic_store(&qp[t], sm, __ATOMIC_RELAXED, __HIP_MEMORY_SCOPE_AGENT);
      }
    }
    __syncthreads();  // drains wave0's agent stores (vmcnt 0 before s_barrier)
    ++arrivals;
    if (tid == 0) {
      __hip_atomic_fetch_add(cnt, 1u, __ATOMIC_RELEASE, __HIP_MEMORY_SCOPE_AGENT);
      const unsigned tgt = SBLK * arrivals;
      int guard = 0;
      while (__hip_atomic_load(cnt, __ATOMIC_ACQUIRE, __HIP_MEMORY_SCOPE_AGENT) < tgt) {
        if (++guard > (1 << 20)) break;  // deadlock escape (should never trigger)
      }
    }
    __syncthreads();
    // ---- wave0 gathers the 8 partials (fixed order -> identical bits everywhere) ----
    if (wv == 0) {
      const float* qb = qpart + (size_t)(par * BDIM + b) * SBLK * 320;
      float Q0 = 0.f, Q1 = 0.f, Q2 = 0.f, Q3 = 0.f, Q4 = 0.f;
#pragma unroll
      for (int cc = 0; cc < SBLK; ++cc) {
        const float* qp = qb + cc * 320;
        Q0 += __hip_atomic_load(&qp[l], __ATOMIC_RELAXED, __HIP_MEMORY_SCOPE_AGENT);
        Q1 += __hip_atomic_load(&qp[64 + l], __ATOMIC_RELAXED, __HIP_MEMORY_SCOPE_AGENT);
        Q2 += __hip_atomic_load(&qp[128 + l], __ATOMIC_RELAXED, __HIP_MEMORY_SCOPE_AGENT);
        Q3 += __hip_atomic_load(&qp[192 + l], __ATOMIC_RELAXED, __HIP_MEMORY_SCOPE_AGENT);
        Q4 += __hip_atomic_load(&qp[256 + l], __ATOMIC_RELAXED, __HIP_MEMORY_SCOPE_AGENT);
      }
      qtot[l] = Q0;
      qtot[64 + l] = Q1;
      qtot[128 + l] = Q2;
      qtot[192 + l] = Q3;
      qtot[256 + l] = Q4;
    }
    __syncthreads();
    const float Q0 = qtot[l], Q1 = qtot[64 + l], Q2 = qtot[128 + l], Q3 = qtot[192 + l],
                Q4 = qtot[256 + l];
    // residual uses PRE-update w (matches previous kernel)
    float r = fabsf(fmaf(Q0 * w0, TN_RATIO, -1.0f));
    r = fmaxf(r, fabsf(fmaf(Q1 * w1, TN_RATIO, -1.0f)));
    r = fmaxf(r, fabsf(fmaf(Q2 * w2, TN_RATIO, -1.0f)));
    r = fmaxf(r, fabsf(fmaf(Q3 * w3, TN_RATIO, -1.0f)));
    if (l < 59) r = fmaxf(r, fabsf(fmaf(Q4 * w4, TN_RATIO, -1.0f)));
    w0 = __builtin_amdgcn_rcpf(Q0);
    w1 = __builtin_amdgcn_rcpf(Q1);
    w2 = __builtin_amdgcn_rcpf(Q2);
    w3 = __builtin_amdgcn_rcpf(Q3);
    if (l < 59) w4 = __builtin_amdgcn_rcpf(Q4);
    if (fin) break;  // fin iteration ends on the col-norm above, like the reference
    r = dppmax<0x111, 0xf>(r);
    r = dppmax<0x112, 0xf>(r);
    r = dppmax<0x114, 0xf>(r);
    r = dppmax<0x118, 0xf>(r);
    r = dppmax<0x142, 0xa>(r);
    r = dppmax<0x143, 0xc>(r);
    const float resid = __int_as_float(__builtin_amdgcn_readlane(__float_as_int(r), 63));
    fin = (resid < TOL) || (it == NITER - 2);
  }

  // ---- epilogue: s1 = a_fin * E * w_fin, written bf16 ----
#pragma unroll
  for (int j = 0; j < SRPW; ++j) {
    unsigned short* row = S1 + (size_t)(r0 + j) * TPAD;
    const float a = aj[j];
    row[l] = bf1(a * E0[j] * w0);
    row[64 + l] = bf1(a * E1[j] * w1);
    row[128 + l] = bf1(a * E2[j] * w2);
    row[192 + l] = bf1(a * E3[j] * w3);
    row[256 + l] = (l < 59) ? bf1(a * E4[j] * w4) : (unsigned short)0;
  }
}

// ---------------- K4: f1[b][t][d] = sum_n s1[b][n][t] * F[b][n][d]  (TN bf16 MFMA) ----------
__global__ __launch_bounds__(256) void k_f1(const unsigned short* __restrict__ s1b,
                                            const unsigned short* __restrict__ Fb,
                                            unsigned short* __restrict__ f1b) {
  __shared__ unsigned short Abf[64 * LDH];  // [t][n]
  __shared__ unsigned short Bbf[64 * LDH];  // [d][n]
  const int tid = threadIdx.x, l = tid & 63, wv = tid >> 6;
  const int d0 = blockIdx.x * 64, t0 = blockIdx.y * 64, bz = blockIdx.z;
  const unsigned short* sb = s1b + (size_t)bz * NDIM * TPAD;
  const unsigned short* Fbb = Fb + (size_t)bz * NDIM * DDIM;
  unsigned short* out = f1b + (size_t)bz * TDIM * DDIM;
  f32x4 acc[4] = {};
  const int col = tid & 31, g = tid >> 5;
  for (int k0 = 0; k0 < 416; k0 += 32) {
    int n = k0 + col;
    uint4 av = make_uint4(0, 0, 0, 0), bv = av;
    if (n < NDIM) {
      av = *(const uint4*)(sb + (size_t)n * TPAD + t0 + g * 8);
      bv = *(const uint4*)(Fbb + (size_t)n * DDIM + d0 + g * 8);
    }
    unsigned short ah[8], bh8[8];
    *(uint4*)ah = av;
    *(uint4*)bh8 = bv;
#pragma unroll
    for (int i = 0; i < 8; ++i) {
      Abf[(g * 8 + i) * LDH + col] = ah[i];
      Bbf[(g * 8 + i) * LDH + col] = bh8[i];
    }
    __syncthreads();
    bf16x8 af = *(const bf16x8*)(&Abf[(wv * 16 + (l & 15)) * LDH + (l >> 4) * 8]);
#pragma unroll
    for (int c = 0; c < 4; ++c) {
      bf16x8 bf_ = *(const bf16x8*)(&Bbf[(c * 16 + (l & 15)) * LDH + (l >> 4) * 8]);
      acc[c] = __builtin_amdgcn_mfma_f32_16x16x32_bf16(af, bf_, acc[c], 0, 0, 0);
    }
    __syncthreads();
  }
#pragma unroll
  for (int c = 0; c < 4; ++c)
#pragma unroll
    for (int r = 0; r < 4; ++r) {
      int t = t0 + wv * 16 + ((l >> 4) << 2) + r;
      int d = d0 + c * 16 + (l & 15);
      if (t < TDIM) out[(size_t)t * DDIM + d] = bf1(acc[c][r]);
    }
}

// ---------------- K5: fused h + pred (Wh pre-packed bf16) ----------------
__global__ __launch_bounds__(256) void k_hp(const unsigned short* __restrict__ f1b,
                                            const unsigned short* __restrict__ Whb,
                                            const float* __restrict__ TB,
                                            const float* __restrict__ Wo,
                                            const float* __restrict__ bo,
                                            float* __restrict__ out) {
  __shared__ unsigned short Abf[64 * LDH];  // [r][d]
  __shared__ unsigned short Bbf[64 * LDH];  // [j][d]
  __shared__ float Wos[64];
  const int tid = threadIdx.x, l = tid & 63, wv = tid >> 6;
  const int j0 = blockIdx.x * 64, r0 = blockIdx.y * 64;
  const int RTOT = BDIM * TDIM;  // 10080
  if (tid < 64) Wos[tid] = Wo[j0 + tid];
  f32x4 acc[4] = {};
  const int m = tid >> 2, kq = (tid & 3) * 8;
  const int col = tid & 31, g = tid >> 5;
  for (int k0 = 0; k0 < 512; k0 += 32) {
    uint4 av = make_uint4(0, 0, 0, 0);
    int r = r0 + m;
    if (r < RTOT) av = *(const uint4*)(f1b + (size_t)r * DDIM + k0 + kq);
    *(uint4*)(&Abf[m * LDH + kq]) = av;
    uint4 bv = *(const uint4*)(Whb + (size_t)(k0 + col) * HDIM + j0 + g * 8);
    unsigned short bh8[8];
    *(uint4*)bh8 = bv;
#pragma unroll
    for (int i = 0; i < 8; ++i) Bbf[(g * 8 + i) * LDH + col] = bh8[i];
    __syncthreads();
    bf16x8 af = *(const bf16x8*)(&Abf[(wv * 16 + (l & 15)) * LDH + (l >> 4) * 8]);
#pragma unroll
    for (int c = 0; c < 4; ++c) {
      bf16x8 bf_ = *(const bf16x8*)(&Bbf[(c * 16 + (l & 15)) * LDH + (l >> 4) * 8]);
      acc[c] = __builtin_amdgcn_mfma_f32_16x16x32_bf16(af, bf_, acc[c], 0, 0, 0);
    }
    __syncthreads();
  }
  int tmod[4];
#pragma unroll
  for (int r = 0; r < 4; ++r) {
    int rr = r0 + wv * 16 + ((l >> 4) << 2) + r;
    tmod[r] = rr % TDIM;
  }
  float part[4] = {0.f, 0.f, 0.f, 0.f};
#pragma unroll
  for (int c = 0; c < 4; ++c) {
    int jl = c * 16 + (l & 15);
    float woc = Wos[jl];
#pragma unroll
    for (int r = 0; r < 4; ++r) {
      float v = acc[c][r] + TB[(size_t)tmod[r] * HDIM + j0 + jl];
      part[r] = fmaf(fmaxf(v, 0.f), woc, part[r]);
    }
  }
#pragma unroll
  for (int r = 0; r < 4; ++r) part[r] = dppadd<0x111, 0xf>(part[r]);
#pragma unroll
  for (int r = 0; r < 4; ++r) part[r] = dppadd<0x112, 0xf>(part[r]);
#pragma unroll
  for (int r = 0; r < 4; ++r) part[r] = dppadd<0x114, 0xf>(part[r]);
#pragma unroll
  for (int r = 0; r < 4; ++r) part[r] = dppadd<0x118, 0xf>(part[r]);
  if ((l & 15) == 15) {
    float base = (j0 == 0) ? bo[0] : 0.0f;
#pragma unroll
    for (int r = 0; r < 4; ++r) {
      int rr = r0 + wv * 16 + ((l >> 4) << 2) + r;
      if (rr < RTOT) atomicAdd(&out[rr], part[r] + base);
    }
  }
}

// ---------------- launch ----------------
extern "C" void kernel_launch(void* const* d_in, const int* in_sizes, int n_in,
                              void* d_out, int out_size, void* d_ws, size_t ws_size,
                              hipStream_t stream) {
  const float* F     = (const float*)d_in[0];
  const float* text  = (const float*)d_in[1];
  const float* A     = (const float*)d_in[2];
  const float* gamma = (const float*)d_in[3];
  const float* beta  = (const float*)d_in[4];
  const float* Wh    = (const float*)d_in[5];
  const float* bh    = (const float*)d_in[6];
  const float* Wo    = (const float*)d_in[7];
  const float* bo    = (const float*)d_in[8];
  float* out = (float*)d_out;
  char* ws = (char*)d_ws;
  unsigned short* tAb = (unsigned short*)(ws + OFS_TAB);
  float* TB    = (float*)(ws + OFS_TB);
  float* stats = (float*)(ws + OFS_STATS);
  unsigned short* Whb = (unsigned short*)(ws + OFS_WHB);
  __half* sbuf = (__half*)(ws + OFS_S);
  unsigned short* s1b = (unsigned short*)(ws + OFS_S1B);
  unsigned short* f1b = (unsigned short*)(ws + OFS_F1);
  unsigned short* Fb  = (unsigned short*)(ws + OFS_FB);
  unsigned* qbar = (unsigned*)(ws + OFS_QBAR);
  float* qpart   = (float*)(ws + OFS_QPART);

  hipMemsetAsync(stats, 0, BDIM * 2 * sizeof(float), stream);
  hipMemsetAsync(qbar, 0, 32 * 16 * sizeof(unsigned), stream);
  hipMemsetAsync(out, 0, (size_t)out_size * sizeof(float), stream);
  k_pack<<<512, 256, 0, stream>>>(F, Wh, Fb, Whb);
  k_pre<<<dim3(8, 5, 2), 256, 0, stream>>>(text, A, Wh, bh, tAb, TB);
  k_s<<<dim3(5, 7, 32), 256, 0, stream>>>(Fb, tAb, sbuf, stats);
  k_sinkhorn<<<dim3(SBLK, BDIM), 320, 0, stream>>>(sbuf, stats, gamma, beta, s1b, qpart, qbar);
  k_f1<<<dim3(8, 5, 32), 256, 0, stream>>>(s1b, Fb, f1b);
  k_hp<<<dim3(4, 158), 256, 0, stream>>>(f1b, Whb, TB, Wo, bo, out);
}

// Round 2
// 250.945 us; speedup vs baseline: 1.1301x; 1.0673x over previous
//
#include <hip/hip_runtime.h>
#include <hip/hip_fp16.h>

// Problem dims
#define BDIM 32
#define NDIM 400
#define TDIM 315
#define TPAD 320
#define DDIM 512
#define HDIM 256
#define NITER 100

// Workspace layout (bytes), tightly packed (~41 MB)
#define OFS_TAB   0u          // tAb bf16 [320][512] = 327680
#define OFS_TB    327680u     // TB f32 [320][256] = 327680
#define OFS_STATS 655360u     // stats[32][2] f32 = 256
#define OFS_WHB   655616u     // Whb bf16 [512][256] = 262144
#define OFS_S     1048576u    // s fp16 [32][400][320] = 8192000
#define OFS_S1B   9240576u    // s1b bf16 [32][400][320] = 8192000
#define OFS_F1    17432576u   // f1b bf16 [32][315][512] = 10321920  (end 27754496)
#define OFS_FB    27754496u   // Fb bf16 [32][400][512] = 13107200  (end 40861696)
// k_sinkhorn scratch overlaps the f1b region (f1b is produced AFTER sinkhorn):
#define OFS_QBAR  OFS_F1            // flags: 32 batches x 16 u32 (64B stride) = 2048
#define OFS_QPART (OFS_F1 + 4096u)  // q partials f32 [2][32][8][320] = 655360

typedef __attribute__((ext_vector_type(8))) short bf16x8;
typedef __attribute__((ext_vector_type(4))) float f32x4;

// ---------------- bf16 pack/unpack (RNE) ----------------
__device__ __forceinline__ unsigned rne_hi(float x) {
  unsigned u = __float_as_uint(x);
  u += 0x7fffu + ((u >> 16) & 1u);
  return u & 0xffff0000u;
}
__device__ __forceinline__ unsigned pack2(float lo, float hi) {
  return (rne_hi(lo) >> 16) | rne_hi(hi);
}
__device__ __forceinline__ unsigned short bf1(float x) { return (unsigned short)(rne_hi(x) >> 16); }

// ---------------- DPP wave reduce helpers (VALU pipe, no LDS) ----------------
template <int CTRL, int RMASK>
__device__ __forceinline__ float dppadd(float x) {
  int y = __builtin_amdgcn_update_dpp(0, __float_as_int(x), CTRL, RMASK, 0xf, true);
  return x + __int_as_float(y);
}
template <int CTRL, int RMASK>
__device__ __forceinline__ float dppmax(float x) {
  int y = __builtin_amdgcn_update_dpp(0, __float_as_int(x), CTRL, RMASK, 0xf, true);
  return fmaxf(x, __int_as_float(y));
}

// ---------------- K0: bf16 packing of F/Wh_top + zero-init of out/stats/flags --------------
__global__ void k_pack(const float* __restrict__ F, const float* __restrict__ Wh,
                       unsigned short* __restrict__ Fb, unsigned short* __restrict__ Whb,
                       float* __restrict__ out, int out_n, float* __restrict__ stats,
                       unsigned* __restrict__ qbar) {
  const int NF4 = (BDIM * NDIM * DDIM) / 4;  // 1638400
  const int NW4 = (DDIM * HDIM) / 4;         // 32768 (top half of Wh is the first 512*256)
  int tid0 = blockIdx.x * blockDim.x + threadIdx.x;
  int stride = gridDim.x * blockDim.x;
  for (int i = tid0; i < NF4; i += stride) {
    float4 v = ((const float4*)F)[i];
    ((uint2*)Fb)[i] = make_uint2(pack2(v.x, v.y), pack2(v.z, v.w));
  }
  for (int i = tid0; i < NW4; i += stride) {
    float4 v = ((const float4*)Wh)[i];
    ((uint2*)Whb)[i] = make_uint2(pack2(v.x, v.y), pack2(v.z, v.w));
  }
  for (int i = tid0; i < out_n; i += stride) out[i] = 0.0f;
  if (tid0 < BDIM * 2) stats[tid0] = 0.0f;
  if (tid0 < BDIM * 16) qbar[tid0] = 0u;
}

// ---------------- fp32 GEMM pieces (k_pre only) ----------------
__device__ __forceinline__ void mm_inner(const float* __restrict__ As, const float* __restrict__ Bs,
                                         float acc[4][4], int tm, int tn) {
#pragma unroll
  for (int k = 0; k < 32; ++k) {
    float4 a = *(const float4*)(As + k * 72 + tm * 4);
    float4 b = *(const float4*)(Bs + k * 72 + tn * 4);
    float ar[4] = {a.x, a.y, a.z, a.w};
    float br[4] = {b.x, b.y, b.z, b.w};
#pragma unroll
    for (int i = 0; i < 4; ++i)
#pragma unroll
      for (int j = 0; j < 4; ++j)
        acc[i][j] = fmaf(ar[i], br[j], acc[i][j]);
  }
}

__device__ __forceinline__ void stage_T(float* __restrict__ Xs, const float* __restrict__ X,
                                        int r0, int ld, int k0, int tid, int rmax) {
  int kq = tid & 7;
  int mb = tid >> 3;
#pragma unroll
  for (int p = 0; p < 2; ++p) {
    int mm = mb + 32 * p;
    int row = r0 + mm;
    float4 v = make_float4(0.f, 0.f, 0.f, 0.f);
    if (row < rmax) v = *(const float4*)(X + (size_t)row * ld + k0 + 4 * kq);
    Xs[(4 * kq + 0) * 72 + mm] = v.x;
    Xs[(4 * kq + 1) * 72 + mm] = v.y;
    Xs[(4 * kq + 2) * 72 + mm] = v.z;
    Xs[(4 * kq + 3) * 72 + mm] = v.w;
  }
}

__device__ __forceinline__ void stage_N(float* __restrict__ Ws, const float* __restrict__ W,
                                        int k0, int ld, int n0, int tid, int kmax) {
  int nq = tid & 15;
  int kk = tid >> 4;
#pragma unroll
  for (int p = 0; p < 2; ++p) {
    int k = kk + 16 * p;
    float4 v = make_float4(0.f, 0.f, 0.f, 0.f);
    if (k0 + k < kmax) v = *(const float4*)(W + (size_t)(k0 + k) * ld + n0 + 4 * nq);
    *(float4*)(Ws + k * 72 + 4 * nq) = v;
  }
}

// ---------------- K1: merged tA (z=0, bf16 out) + TB (z=1) ----------------
__global__ void k_pre(const float* __restrict__ text, const float* __restrict__ A,
                      const float* __restrict__ Wh, const float* __restrict__ bh,
                      unsigned short* __restrict__ tAb, float* __restrict__ TB) {
  __shared__ float Xs[32 * 72], Ys[32 * 72];
  int tid = threadIdx.x, tm = tid >> 4, tn = tid & 15;
  if (blockIdx.z == 0) {
    int d0 = blockIdx.x * 64, t0 = blockIdx.y * 64;
    float acc[4][4] = {};
    for (int k0 = 0; k0 < 512; k0 += 32) {
      stage_T(Xs, text, t0, 512, k0, tid, TDIM);
      stage_T(Ys, A, d0, 512, k0, tid, 512);
      __syncthreads();
      mm_inner(Xs, Ys, acc, tm, tn);
      __syncthreads();
    }
#pragma unroll
    for (int i = 0; i < 4; ++i) {
      int t = t0 + tm * 4 + i;  // pad rows (>=315) get zeros (Xs zero-filled)
      *(uint2*)(tAb + (size_t)t * 512 + d0 + tn * 4) =
          make_uint2(pack2(acc[i][0], acc[i][1]), pack2(acc[i][2], acc[i][3]));
    }
  } else {
    if (blockIdx.x >= 4) return;
    int h0 = blockIdx.x * 64, t0 = blockIdx.y * 64;
    const float* Wb = Wh + 512 * 256;
    float acc[4][4] = {};
    for (int k0 = 0; k0 < 512; k0 += 32) {
      stage_T(Xs, text, t0, 512, k0, tid, TDIM);
      stage_N(Ys, Wb, k0, 256, h0, tid, 512);
      __syncthreads();
      mm_inner(Xs, Ys, acc, tm, tn);
      __syncthreads();
    }
#pragma unroll
    for (int i = 0; i < 4; ++i) {
      int t = t0 + tm * 4 + i;
      int h = h0 + tn * 4;
      *(float4*)(TB + (size_t)t * 256 + h) =
          make_float4(acc[i][0] + bh[h], acc[i][1] + bh[h + 1],
                      acc[i][2] + bh[h + 2], acc[i][3] + bh[h + 3]);
    }
  }
}

// ================= MFMA GEMMs: 64x64 tile, 256 thr (4 waves), 16x16x32 bf16 =================
#define LDH 40

// ---------------- K2: s[b][n][t] (fp16 out) + instnorm stats; operands pre-packed bf16 ------
__global__ __launch_bounds__(256) void k_s(const unsigned short* __restrict__ Fb,
                                           const unsigned short* __restrict__ tAb,
                                           __half* __restrict__ s, float* __restrict__ stats) {
  __shared__ unsigned short Abf[64 * LDH];
  __shared__ unsigned short Bbf[64 * LDH];
  __shared__ float red[8];
  const int tid = threadIdx.x, l = tid & 63, wv = tid >> 6;
  const int t0 = blockIdx.x * 64, n0 = blockIdx.y * 64, bz = blockIdx.z;
  const unsigned short* Fbb = Fb + (size_t)bz * NDIM * DDIM;
  __half* sb = s + (size_t)bz * NDIM * TPAD;
  f32x4 acc[4] = {};
  const int m = tid >> 2, kq = (tid & 3) * 8;
  for (int k0 = 0; k0 < 512; k0 += 32) {
    uint4 av = make_uint4(0, 0, 0, 0);
    int n = n0 + m;
    if (n < NDIM) av = *(const uint4*)(Fbb + (size_t)n * DDIM + k0 + kq);
    *(uint4*)(&Abf[m * LDH + kq]) = av;
    uint4 bv = *(const uint4*)(tAb + (size_t)(t0 + m) * DDIM + k0 + kq);
    *(uint4*)(&Bbf[m * LDH + kq]) = bv;
    __syncthreads();
    bf16x8 af = *(const bf16x8*)(&Abf[(wv * 16 + (l & 15)) * LDH + (l >> 4) * 8]);
#pragma unroll
    for (int c = 0; c < 4; ++c) {
      bf16x8 bf_ = *(const bf16x8*)(&Bbf[(c * 16 + (l & 15)) * LDH + (l >> 4) * 8]);
      acc[c] = __builtin_amdgcn_mfma_f32_16x16x32_bf16(af, bf_, acc[c], 0, 0, 0);
    }
    __syncthreads();
  }
  float lsum = 0.f, lsq = 0.f;
#pragma unroll
  for (int c = 0; c < 4; ++c)
#pragma unroll
    for (int r = 0; r < 4; ++r) {
      int n = n0 + wv * 16 + ((l >> 4) << 2) + r;
      int t = t0 + c * 16 + (l & 15);
      if (n < NDIM && t < TDIM) {
        float v = acc[c][r];
        sb[(size_t)n * TPAD + t] = __float2half(v);
        lsum += v;
        lsq = fmaf(v, v, lsq);
      }
    }
#pragma unroll
  for (int mm = 1; mm <= 32; mm <<= 1) {
    lsum += __shfl_xor(lsum, mm, 64);
    lsq += __shfl_xor(lsq, mm, 64);
  }
  if ((tid & 63) == 0) { red[wv * 2] = lsum; red[wv * 2 + 1] = lsq; }
  __syncthreads();
  if (tid == 0) {
    float S = red[0] + red[2] + red[4] + red[6];
    float Q = red[1] + red[3] + red[5] + red[7];
    atomicAdd(&stats[bz * 2], S);
    atomicAdd(&stats[bz * 2 + 1], Q);
  }
}

// ---------------- K3: multi-CU sinkhorn (flag barrier, XCD co-located) ----------------------
// 8 blocks per batch, grid (b, c) so partner blocks share linear-id mod 8 -> same XCD.
// Exchange per iteration: relaxed partial stores -> ONE release fence -> relaxed flag store;
// readers poll flags RELAXED (no per-poll cache maintenance) -> ONE acquire fence -> gather.
// Flags are monotone (it+1); partials double-buffered by parity. Correctness: block A writes
// buf[k&1] for iter k+2 only after seeing flag>=k+2 from every partner, which each partner
// release-publishes only after its gather of buf[k&1] (release fence orders prior loads).
#define SBLK 8
#define SROWS 50
#define SRPW 10

__global__ __launch_bounds__(320, 1) void k_sinkhorn(const __half* __restrict__ sbuf,
                                                     const float* __restrict__ stats,
                                                     const float* __restrict__ gptr,
                                                     const float* __restrict__ bptr,
                                                     unsigned short* __restrict__ s1b,
                                                     float* __restrict__ qpart,
                                                     unsigned* __restrict__ qbar) {
  __shared__ float qpl[5][320];   // per-wave col partials
  __shared__ float qtot[320];     // broadcast of summed col totals
  const int b = blockIdx.x, c = blockIdx.y;
  const int tid = threadIdx.x, wv = tid >> 6, l = tid & 63;
  const __half* S = sbuf + (size_t)b * NDIM * TPAD;
  unsigned short* S1 = s1b + (size_t)b * NDIM * TPAD;
  const float NT = 400.0f * 315.0f;
  const float mean = stats[2 * b] / NT;
  const float var = stats[2 * b + 1] / NT - mean * mean;
  const float inv = rsqrtf(var + 1e-5f);
  const float alpha = gptr[0] * inv;
  const float L2E = 1.4426950408889634f;
  const float a2 = alpha * L2E;
  const float d2 = (bptr[0] - mean * alpha) * L2E;
  const int r0 = c * SROWS + wv * SRPW;
  const float TOL = 1e-3f;
  const float TN_RATIO = 315.0f / 400.0f;
  unsigned* flg = qbar + b * 16;  // 64B stride per batch; 8 flags in one line

  // ---- prologue: E = exp(instnorm(s)) into registers, fp32, 5 cols/lane x 10 rows ----
  float E0[SRPW], E1[SRPW], E2[SRPW], E3[SRPW], E4[SRPW];
#pragma unroll
  for (int j = 0; j < SRPW; ++j) {
    const __half* row = S + (size_t)(r0 + j) * TPAD;
    E0[j] = __builtin_amdgcn_exp2f(fmaf(__half2float(row[l]), a2, d2));
    E1[j] = __builtin_amdgcn_exp2f(fmaf(__half2float(row[64 + l]), a2, d2));
    E2[j] = __builtin_amdgcn_exp2f(fmaf(__half2float(row[128 + l]), a2, d2));
    E3[j] = __builtin_amdgcn_exp2f(fmaf(__half2float(row[192 + l]), a2, d2));
    E4[j] = (l < 59) ? __builtin_amdgcn_exp2f(fmaf(__half2float(row[256 + l]), a2, d2)) : 0.0f;
  }
  float w0 = 1.0f, w1 = 1.0f, w2 = 1.0f, w3 = 1.0f, w4 = (l < 59) ? 1.0f : 0.0f;
  float aj[SRPW];
#pragma unroll
  for (int j = 0; j < SRPW; ++j) aj[j] = 0.0f;

  bool fin = false;
  for (int it = 0; it < NITER; ++it) {
    // ---- row sums p = E . w (registers only) ----
    float p[SRPW];
#pragma unroll
    for (int j = 0; j < SRPW; ++j) {
      float t = E4[j] * w4;
      t = fmaf(E3[j], w3, t);
      t = fmaf(E2[j], w2, t);
      t = fmaf(E1[j], w1, t);
      p[j] = fmaf(E0[j], w0, t);
    }
#pragma unroll
    for (int j = 0; j < SRPW; ++j) p[j] = dppadd<0x111, 0xf>(p[j]);
#pragma unroll
    for (int j = 0; j < SRPW; ++j) p[j] = dppadd<0x112, 0xf>(p[j]);
#pragma unroll
    for (int j = 0; j < SRPW; ++j) p[j] = dppadd<0x114, 0xf>(p[j]);
#pragma unroll
    for (int j = 0; j < SRPW; ++j) p[j] = dppadd<0x118, 0xf>(p[j]);
#pragma unroll
    for (int j = 0; j < SRPW; ++j) p[j] = dppadd<0x142, 0xa>(p[j]);
#pragma unroll
    for (int j = 0; j < SRPW; ++j) p[j] = dppadd<0x143, 0xc>(p[j]);
#pragma unroll
    for (int j = 0; j < SRPW; ++j) {
      float r = __builtin_amdgcn_rcpf(p[j]);
      aj[j] = __int_as_float(__builtin_amdgcn_readlane(__float_as_int(r), 63));
    }
    // ---- local col partials q = E^T . a ----
    float q0 = 0.f, q1 = 0.f, q2 = 0.f, q3 = 0.f, q4 = 0.f;
#pragma unroll
    for (int j = 0; j < SRPW; ++j) {
      q0 = fmaf(E0[j], aj[j], q0);
      q1 = fmaf(E1[j], aj[j], q1);
      q2 = fmaf(E2[j], aj[j], q2);
      q3 = fmaf(E3[j], aj[j], q3);
      q4 = fmaf(E4[j], aj[j], q4);
    }
    qpl[wv][l] = q0;
    qpl[wv][64 + l] = q1;
    qpl[wv][128 + l] = q2;
    qpl[wv][192 + l] = q3;
    qpl[wv][256 + l] = q4;
    __syncthreads();
    const int par = it & 1;
    const unsigned tgt = (unsigned)(it + 1);
    if (wv == 0) {
      // combine 5 waves' partials, publish (relaxed stores + one release fence + flag)
      float* qp = qpart + ((size_t)(par * BDIM + b) * SBLK + c) * 320;
#pragma unroll
      for (int k = 0; k < 5; ++k) {
        int t = k * 64 + l;
        float sm = qpl[0][t] + qpl[1][t] + qpl[2][t] + qpl[3][t] + qpl[4][t];
        __hip_atomic_store(&qp[t], sm, __ATOMIC_RELAXED, __HIP_MEMORY_SCOPE_AGENT);
      }
      __builtin_amdgcn_fence(__ATOMIC_RELEASE, "agent");
      if (l == 0)
        __hip_atomic_store(&flg[c], tgt, __ATOMIC_RELAXED, __HIP_MEMORY_SCOPE_AGENT);
      // poll: lanes 0..7 watch one flag each, relaxed (no per-poll cache maintenance)
      int guard = 0;
      for (;;) {
        unsigned v = tgt;
        if (l < SBLK)
          v = __hip_atomic_load(&flg[l], __ATOMIC_RELAXED, __HIP_MEMORY_SCOPE_AGENT);
        if (__ballot(v >= tgt) == ~0ull) break;
        if (++guard > (1 << 20)) break;  // deadlock escape (should never trigger)
      }
      __builtin_amdgcn_fence(__ATOMIC_ACQUIRE, "agent");
      // gather the 8 partials (fixed order -> identical bits in every block)
      const float* qb = qpart + (size_t)(par * BDIM + b) * SBLK * 320;
      float Q0 = 0.f, Q1 = 0.f, Q2 = 0.f, Q3 = 0.f, Q4 = 0.f;
#pragma unroll
      for (int cc = 0; cc < SBLK; ++cc) {
        const float* qp = qb + cc * 320;
        Q0 += __hip_atomic_load(&qp[l], __ATOMIC_RELAXED, __HIP_MEMORY_SCOPE_AGENT);
        Q1 += __hip_atomic_load(&qp[64 + l], __ATOMIC_RELAXED, __HIP_MEMORY_SCOPE_AGENT);
        Q2 += __hip_atomic_load(&qp[128 + l], __ATOMIC_RELAXED, __HIP_MEMORY_SCOPE_AGENT);
        Q3 += __hip_atomic_load(&qp[192 + l], __ATOMIC_RELAXED, __HIP_MEMORY_SCOPE_AGENT);
        Q4 += __hip_atomic_load(&qp[256 + l], __ATOMIC_RELAXED, __HIP_MEMORY_SCOPE_AGENT);
      }
      qtot[l] = Q0;
      qtot[64 + l] = Q1;
      qtot[128 + l] = Q2;
      qtot[192 + l] = Q3;
      qtot[256 + l] = Q4;
    }
    __syncthreads();
    const float Q0 = qtot[l], Q1 = qtot[64 + l], Q2 = qtot[128 + l], Q3 = qtot[192 + l],
                Q4 = qtot[256 + l];
    // residual uses PRE-update w (matches previous kernel)
    float r = fabsf(fmaf(Q0 * w0, TN_RATIO, -1.0f));
    r = fmaxf(r, fabsf(fmaf(Q1 * w1, TN_RATIO, -1.0f)));
    r = fmaxf(r, fabsf(fmaf(Q2 * w2, TN_RATIO, -1.0f)));
    r = fmaxf(r, fabsf(fmaf(Q3 * w3, TN_RATIO, -1.0f)));
    if (l < 59) r = fmaxf(r, fabsf(fmaf(Q4 * w4, TN_RATIO, -1.0f)));
    w0 = __builtin_amdgcn_rcpf(Q0);
    w1 = __builtin_amdgcn_rcpf(Q1);
    w2 = __builtin_amdgcn_rcpf(Q2);
    w3 = __builtin_amdgcn_rcpf(Q3);
    if (l < 59) w4 = __builtin_amdgcn_rcpf(Q4);
    if (fin) break;  // fin iteration ends on the col-norm above, like the reference
    r = dppmax<0x111, 0xf>(r);
    r = dppmax<0x112, 0xf>(r);
    r = dppmax<0x114, 0xf>(r);
    r = dppmax<0x118, 0xf>(r);
    r = dppmax<0x142, 0xa>(r);
    r = dppmax<0x143, 0xc>(r);
    const float resid = __int_as_float(__builtin_amdgcn_readlane(__float_as_int(r), 63));
    fin = (resid < TOL) || (it == NITER - 2);
  }

  // ---- epilogue: s1 = a_fin * E * w_fin, written bf16 ----
#pragma unroll
  for (int j = 0; j < SRPW; ++j) {
    unsigned short* row = S1 + (size_t)(r0 + j) * TPAD;
    const float a = aj[j];
    row[l] = bf1(a * E0[j] * w0);
    row[64 + l] = bf1(a * E1[j] * w1);
    row[128 + l] = bf1(a * E2[j] * w2);
    row[192 + l] = bf1(a * E3[j] * w3);
    row[256 + l] = (l < 59) ? bf1(a * E4[j] * w4) : (unsigned short)0;
  }
}

// ---------------- K4: f1[b][t][d] = sum_n s1[b][n][t] * F[b][n][d]  (TN bf16 MFMA) ----------
__global__ __launch_bounds__(256) void k_f1(const unsigned short* __restrict__ s1b,
                                            const unsigned short* __restrict__ Fb,
                                            unsigned short* __restrict__ f1b) {
  __shared__ unsigned short Abf[64 * LDH];  // [t][n]
  __shared__ unsigned short Bbf[64 * LDH];  // [d][n]
  const int tid = threadIdx.x, l = tid & 63, wv = tid >> 6;
  const int d0 = blockIdx.x * 64, t0 = blockIdx.y * 64, bz = blockIdx.z;
  const unsigned short* sb = s1b + (size_t)bz * NDIM * TPAD;
  const unsigned short* Fbb = Fb + (size_t)bz * NDIM * DDIM;
  unsigned short* out = f1b + (size_t)bz * TDIM * DDIM;
  f32x4 acc[4] = {};
  const int col = tid & 31, g = tid >> 5;
  for (int k0 = 0; k0 < 416; k0 += 32) {
    int n = k0 + col;
    uint4 av = make_uint4(0, 0, 0, 0), bv = av;
    if (n < NDIM) {
      av = *(const uint4*)(sb + (size_t)n * TPAD + t0 + g * 8);
      bv = *(const uint4*)(Fbb + (size_t)n * DDIM + d0 + g * 8);
    }
    unsigned short ah[8], bh8[8];
    *(uint4*)ah = av;
    *(uint4*)bh8 = bv;
#pragma unroll
    for (int i = 0; i < 8; ++i) {
      Abf[(g * 8 + i) * LDH + col] = ah[i];
      Bbf[(g * 8 + i) * LDH + col] = bh8[i];
    }
    __syncthreads();
    bf16x8 af = *(const bf16x8*)(&Abf[(wv * 16 + (l & 15)) * LDH + (l >> 4) * 8]);
#pragma unroll
    for (int c = 0; c < 4; ++c) {
      bf16x8 bf_ = *(const bf16x8*)(&Bbf[(c * 16 + (l & 15)) * LDH + (l >> 4) * 8]);
      acc[c] = __builtin_amdgcn_mfma_f32_16x16x32_bf16(af, bf_, acc[c], 0, 0, 0);
    }
    __syncthreads();
  }
#pragma unroll
  for (int c = 0; c < 4; ++c)
#pragma unroll
    for (int r = 0; r < 4; ++r) {
      int t = t0 + wv * 16 + ((l >> 4) << 2) + r;
      int d = d0 + c * 16 + (l & 15);
      if (t < TDIM) out[(size_t)t * DDIM + d] = bf1(acc[c][r]);
    }
}

// ---------------- K5: fused h + pred (Wh pre-packed bf16) ----------------
__global__ __launch_bounds__(256) void k_hp(const unsigned short* __restrict__ f1b,
                                            const unsigned short* __restrict__ Whb,
                                            const float* __restrict__ TB,
                                            const float* __restrict__ Wo,
                                            const float* __restrict__ bo,
                                            float* __restrict__ out) {
  __shared__ unsigned short Abf[64 * LDH];  // [r][d]
  __shared__ unsigned short Bbf[64 * LDH];  // [j][d]
  __shared__ float Wos[64];
  const int tid = threadIdx.x, l = tid & 63, wv = tid >> 6;
  const int j0 = blockIdx.x * 64, r0 = blockIdx.y * 64;
  const int RTOT = BDIM * TDIM;  // 10080
  if (tid < 64) Wos[tid] = Wo[j0 + tid];
  f32x4 acc[4] = {};
  const int m = tid >> 2, kq = (tid & 3) * 8;
  const int col = tid & 31, g = tid >> 5;
  for (int k0 = 0; k0 < 512; k0 += 32) {
    uint4 av = make_uint4(0, 0, 0, 0);
    int r = r0 + m;
    if (r < RTOT) av = *(const uint4*)(f1b + (size_t)r * DDIM + k0 + kq);
    *(uint4*)(&Abf[m * LDH + kq]) = av;
    uint4 bv = *(const uint4*)(Whb + (size_t)(k0 + col) * HDIM + j0 + g * 8);
    unsigned short bh8[8];
    *(uint4*)bh8 = bv;
#pragma unroll
    for (int i = 0; i < 8; ++i) Bbf[(g * 8 + i) * LDH + col] = bh8[i];
    __syncthreads();
    bf16x8 af = *(const bf16x8*)(&Abf[(wv * 16 + (l & 15)) * LDH + (l >> 4) * 8]);
#pragma unroll
    for (int c = 0; c < 4; ++c) {
      bf16x8 bf_ = *(const bf16x8*)(&Bbf[(c * 16 + (l & 15)) * LDH + (l >> 4) * 8]);
      acc[c] = __builtin_amdgcn_mfma_f32_16x16x32_bf16(af, bf_, acc[c], 0, 0, 0);
    }
    __syncthreads();
  }
  int tmod[4];
#pragma unroll
  for (int r = 0; r < 4; ++r) {
    int rr = r0 + wv * 16 + ((l >> 4) << 2) + r;
    tmod[r] = rr % TDIM;
  }
  float part[4] = {0.f, 0.f, 0.f, 0.f};
#pragma unroll
  for (int c = 0; c < 4; ++c) {
    int jl = c * 16 + (l & 15);
    float woc = Wos[jl];
#pragma unroll
    for (int r = 0; r < 4; ++r) {
      float v = acc[c][r] + TB[(size_t)tmod[r] * HDIM + j0 + jl];
      part[r] = fmaf(fmaxf(v, 0.f), woc, part[r]);
    }
  }
#pragma unroll
  for (int r = 0; r < 4; ++r) part[r] = dppadd<0x111, 0xf>(part[r]);
#pragma unroll
  for (int r = 0; r < 4; ++r) part[r] = dppadd<0x112, 0xf>(part[r]);
#pragma unroll
  for (int r = 0; r < 4; ++r) part[r] = dppadd<0x114, 0xf>(part[r]);
#pragma unroll
  for (int r = 0; r < 4; ++r) part[r] = dppadd<0x118, 0xf>(part[r]);
  if ((l & 15) == 15) {
    float base = (j0 == 0) ? bo[0] : 0.0f;
#pragma unroll
    for (int r = 0; r < 4; ++r) {
      int rr = r0 + wv * 16 + ((l >> 4) << 2) + r;
      if (rr < RTOT) atomicAdd(&out[rr], part[r] + base);
    }
  }
}

// ---------------- launch ----------------
extern "C" void kernel_launch(void* const* d_in, const int* in_sizes, int n_in,
                              void* d_out, int out_size, void* d_ws, size_t ws_size,
                              hipStream_t stream) {
  const float* F     = (const float*)d_in[0];
  const float* text  = (const float*)d_in[1];
  const float* A     = (const float*)d_in[2];
  const float* gamma = (const float*)d_in[3];
  const float* beta  = (const float*)d_in[4];
  const float* Wh    = (const float*)d_in[5];
  const float* bh    = (const float*)d_in[6];
  const float* Wo    = (const float*)d_in[7];
  const float* bo    = (const float*)d_in[8];
  float* out = (float*)d_out;
  char* ws = (char*)d_ws;
  unsigned short* tAb = (unsigned short*)(ws + OFS_TAB);
  float* TB    = (float*)(ws + OFS_TB);
  float* stats = (float*)(ws + OFS_STATS);
  unsigned short* Whb = (unsigned short*)(ws + OFS_WHB);
  __half* sbuf = (__half*)(ws + OFS_S);
  unsigned short* s1b = (unsigned short*)(ws + OFS_S1B);
  unsigned short* f1b = (unsigned short*)(ws + OFS_F1);
  unsigned short* Fb  = (unsigned short*)(ws + OFS_FB);
  unsigned* qbar = (unsigned*)(ws + OFS_QBAR);
  float* qpart   = (float*)(ws + OFS_QPART);

  k_pack<<<512, 256, 0, stream>>>(F, Wh, Fb, Whb, out, out_size, stats, qbar);
  k_pre<<<dim3(8, 5, 2), 256, 0, stream>>>(text, A, Wh, bh, tAb, TB);
  k_s<<<dim3(5, 7, 32), 256, 0, stream>>>(Fb, tAb, sbuf, stats);
  k_sinkhorn<<<dim3(BDIM, SBLK), 320, 0, stream>>>(sbuf, stats, gamma, beta, s1b, qpart, qbar);
  k_f1<<<dim3(8, 5, 32), 256, 0, stream>>>(s1b, Fb, f1b);
  k_hp<<<dim3(4, 158), 256, 0, stream>>>(f1b, Whb, TB, Wo, bo, out);
}

// Round 3
// 214.399 us; speedup vs baseline: 1.3227x; 1.1705x over previous
//
#include <hip/hip_runtime.h>
#include <hip/hip_fp16.h>

// Problem dims
#define BDIM 32
#define NDIM 400
#define TDIM 315
#define TPAD 320
#define DDIM 512
#define HDIM 256
#define NITER 100

// Workspace layout (bytes), tightly packed (~41 MB)
#define OFS_TAB   0u          // tAb bf16 [320][512] = 327680
#define OFS_TB    327680u     // TB f32 [320][256] = 327680
#define OFS_STATS 655360u     // stats[32][2] f32 = 256
#define OFS_WHB   655616u     // Whb bf16 [512][256] = 262144
#define OFS_S     1048576u    // s fp16 [32][400][320] = 8192000
#define OFS_S1B   9240576u    // s1b bf16 [32][400][320] = 8192000
#define OFS_F1    17432576u   // f1b bf16 [32][315][512] = 10321920  (end 27754496)
#define OFS_FB    27754496u   // Fb bf16 [32][400][512] = 13107200  (end 40861696)
// k_sinkhorn scratch overlaps the f1b region (f1b is produced AFTER sinkhorn):
// qpart: tagged pairs (u32 tag | f32 data) [2 parity][32 b][8 c][320] ull = 1310720 B
#define OFS_QPART (OFS_F1 + 4096u)

typedef __attribute__((ext_vector_type(8))) short bf16x8;
typedef __attribute__((ext_vector_type(4))) float f32x4;
typedef unsigned long long ull;

// ---------------- bf16 pack/unpack (RNE) ----------------
__device__ __forceinline__ unsigned rne_hi(float x) {
  unsigned u = __float_as_uint(x);
  u += 0x7fffu + ((u >> 16) & 1u);
  return u & 0xffff0000u;
}
__device__ __forceinline__ unsigned pack2(float lo, float hi) {
  return (rne_hi(lo) >> 16) | rne_hi(hi);
}
__device__ __forceinline__ unsigned short bf1(float x) { return (unsigned short)(rne_hi(x) >> 16); }

// ---------------- DPP wave reduce helpers (VALU pipe, no LDS) ----------------
template <int CTRL, int RMASK>
__device__ __forceinline__ float dppadd(float x) {
  int y = __builtin_amdgcn_update_dpp(0, __float_as_int(x), CTRL, RMASK, 0xf, true);
  return x + __int_as_float(y);
}
template <int CTRL, int RMASK>
__device__ __forceinline__ float dppmax(float x) {
  int y = __builtin_amdgcn_update_dpp(0, __float_as_int(x), CTRL, RMASK, 0xf, true);
  return fmaxf(x, __int_as_float(y));
}

// ---------------- K0: bf16 packing of F/Wh_top + zero-init of out/stats/qpart --------------
__global__ void k_pack(const float* __restrict__ F, const float* __restrict__ Wh,
                       unsigned short* __restrict__ Fb, unsigned short* __restrict__ Whb,
                       float* __restrict__ out, int out_n, float* __restrict__ stats,
                       uint4* __restrict__ qzero) {
  const int NF4 = (BDIM * NDIM * DDIM) / 4;  // 1638400
  const int NW4 = (DDIM * HDIM) / 4;         // 32768 (top half of Wh is the first 512*256)
  const int NQ4 = (2 * BDIM * 8 * 320 * 2) / 4;  // qpart u32 count / 4 = 81920
  int tid0 = blockIdx.x * blockDim.x + threadIdx.x;
  int stride = gridDim.x * blockDim.x;
  for (int i = tid0; i < NF4; i += stride) {
    float4 v = ((const float4*)F)[i];
    ((uint2*)Fb)[i] = make_uint2(pack2(v.x, v.y), pack2(v.z, v.w));
  }
  for (int i = tid0; i < NW4; i += stride) {
    float4 v = ((const float4*)Wh)[i];
    ((uint2*)Whb)[i] = make_uint2(pack2(v.x, v.y), pack2(v.z, v.w));
  }
  for (int i = tid0; i < out_n; i += stride) out[i] = 0.0f;
  for (int i = tid0; i < NQ4; i += stride) qzero[i] = make_uint4(0u, 0u, 0u, 0u);
  if (tid0 < BDIM * 2) stats[tid0] = 0.0f;
}

// ---------------- fp32 GEMM pieces (k_pre only) ----------------
__device__ __forceinline__ void mm_inner(const float* __restrict__ As, const float* __restrict__ Bs,
                                         float acc[4][4], int tm, int tn) {
#pragma unroll
  for (int k = 0; k < 32; ++k) {
    float4 a = *(const float4*)(As + k * 72 + tm * 4);
    float4 b = *(const float4*)(Bs + k * 72 + tn * 4);
    float ar[4] = {a.x, a.y, a.z, a.w};
    float br[4] = {b.x, b.y, b.z, b.w};
#pragma unroll
    for (int i = 0; i < 4; ++i)
#pragma unroll
      for (int j = 0; j < 4; ++j)
        acc[i][j] = fmaf(ar[i], br[j], acc[i][j]);
  }
}

__device__ __forceinline__ void stage_T(float* __restrict__ Xs, const float* __restrict__ X,
                                        int r0, int ld, int k0, int tid, int rmax) {
  int kq = tid & 7;
  int mb = tid >> 3;
#pragma unroll
  for (int p = 0; p < 2; ++p) {
    int mm = mb + 32 * p;
    int row = r0 + mm;
    float4 v = make_float4(0.f, 0.f, 0.f, 0.f);
    if (row < rmax) v = *(const float4*)(X + (size_t)row * ld + k0 + 4 * kq);
    Xs[(4 * kq + 0) * 72 + mm] = v.x;
    Xs[(4 * kq + 1) * 72 + mm] = v.y;
    Xs[(4 * kq + 2) * 72 + mm] = v.z;
    Xs[(4 * kq + 3) * 72 + mm] = v.w;
  }
}

__device__ __forceinline__ void stage_N(float* __restrict__ Ws, const float* __restrict__ W,
                                        int k0, int ld, int n0, int tid, int kmax) {
  int nq = tid & 15;
  int kk = tid >> 4;
#pragma unroll
  for (int p = 0; p < 2; ++p) {
    int k = kk + 16 * p;
    float4 v = make_float4(0.f, 0.f, 0.f, 0.f);
    if (k0 + k < kmax) v = *(const float4*)(W + (size_t)(k0 + k) * ld + n0 + 4 * nq);
    *(float4*)(Ws + k * 72 + 4 * nq) = v;
  }
}

// ---------------- K1: merged tA (z=0, bf16 out) + TB (z=1) ----------------
__global__ void k_pre(const float* __restrict__ text, const float* __restrict__ A,
                      const float* __restrict__ Wh, const float* __restrict__ bh,
                      unsigned short* __restrict__ tAb, float* __restrict__ TB) {
  __shared__ float Xs[32 * 72], Ys[32 * 72];
  int tid = threadIdx.x, tm = tid >> 4, tn = tid & 15;
  if (blockIdx.z == 0) {
    int d0 = blockIdx.x * 64, t0 = blockIdx.y * 64;
    float acc[4][4] = {};
    for (int k0 = 0; k0 < 512; k0 += 32) {
      stage_T(Xs, text, t0, 512, k0, tid, TDIM);
      stage_T(Ys, A, d0, 512, k0, tid, 512);
      __syncthreads();
      mm_inner(Xs, Ys, acc, tm, tn);
      __syncthreads();
    }
#pragma unroll
    for (int i = 0; i < 4; ++i) {
      int t = t0 + tm * 4 + i;  // pad rows (>=315) get zeros (Xs zero-filled)
      *(uint2*)(tAb + (size_t)t * 512 + d0 + tn * 4) =
          make_uint2(pack2(acc[i][0], acc[i][1]), pack2(acc[i][2], acc[i][3]));
    }
  } else {
    if (blockIdx.x >= 4) return;
    int h0 = blockIdx.x * 64, t0 = blockIdx.y * 64;
    const float* Wb = Wh + 512 * 256;
    float acc[4][4] = {};
    for (int k0 = 0; k0 < 512; k0 += 32) {
      stage_T(Xs, text, t0, 512, k0, tid, TDIM);
      stage_N(Ys, Wb, k0, 256, h0, tid, 512);
      __syncthreads();
      mm_inner(Xs, Ys, acc, tm, tn);
      __syncthreads();
    }
#pragma unroll
    for (int i = 0; i < 4; ++i) {
      int t = t0 + tm * 4 + i;
      int h = h0 + tn * 4;
      *(float4*)(TB + (size_t)t * 256 + h) =
          make_float4(acc[i][0] + bh[h], acc[i][1] + bh[h + 1],
                      acc[i][2] + bh[h + 2], acc[i][3] + bh[h + 3]);
    }
  }
}

// ================= MFMA GEMMs: 64x64 tile, 256 thr (4 waves), 16x16x32 bf16 =================
#define LDH 40

// ---------------- K2: s[b][n][t] (fp16 out) + instnorm stats; operands pre-packed bf16 ------
__global__ __launch_bounds__(256) void k_s(const unsigned short* __restrict__ Fb,
                                           const unsigned short* __restrict__ tAb,
                                           __half* __restrict__ s, float* __restrict__ stats) {
  __shared__ unsigned short Abf[64 * LDH];
  __shared__ unsigned short Bbf[64 * LDH];
  __shared__ float red[8];
  const int tid = threadIdx.x, l = tid & 63, wv = tid >> 6;
  const int t0 = blockIdx.x * 64, n0 = blockIdx.y * 64, bz = blockIdx.z;
  const unsigned short* Fbb = Fb + (size_t)bz * NDIM * DDIM;
  __half* sb = s + (size_t)bz * NDIM * TPAD;
  f32x4 acc[4] = {};
  const int m = tid >> 2, kq = (tid & 3) * 8;
  for (int k0 = 0; k0 < 512; k0 += 32) {
    uint4 av = make_uint4(0, 0, 0, 0);
    int n = n0 + m;
    if (n < NDIM) av = *(const uint4*)(Fbb + (size_t)n * DDIM + k0 + kq);
    *(uint4*)(&Abf[m * LDH + kq]) = av;
    uint4 bv = *(const uint4*)(tAb + (size_t)(t0 + m) * DDIM + k0 + kq);
    *(uint4*)(&Bbf[m * LDH + kq]) = bv;
    __syncthreads();
    bf16x8 af = *(const bf16x8*)(&Abf[(wv * 16 + (l & 15)) * LDH + (l >> 4) * 8]);
#pragma unroll
    for (int c = 0; c < 4; ++c) {
      bf16x8 bf_ = *(const bf16x8*)(&Bbf[(c * 16 + (l & 15)) * LDH + (l >> 4) * 8]);
      acc[c] = __builtin_amdgcn_mfma_f32_16x16x32_bf16(af, bf_, acc[c], 0, 0, 0);
    }
    __syncthreads();
  }
  float lsum = 0.f, lsq = 0.f;
#pragma unroll
  for (int c = 0; c < 4; ++c)
#pragma unroll
    for (int r = 0; r < 4; ++r) {
      int n = n0 + wv * 16 + ((l >> 4) << 2) + r;
      int t = t0 + c * 16 + (l & 15);
      if (n < NDIM && t < TDIM) {
        float v = acc[c][r];
        sb[(size_t)n * TPAD + t] = __float2half(v);
        lsum += v;
        lsq = fmaf(v, v, lsq);
      }
    }
#pragma unroll
  for (int mm = 1; mm <= 32; mm <<= 1) {
    lsum += __shfl_xor(lsum, mm, 64);
    lsq += __shfl_xor(lsq, mm, 64);
  }
  if ((tid & 63) == 0) { red[wv * 2] = lsum; red[wv * 2 + 1] = lsq; }
  __syncthreads();
  if (tid == 0) {
    float S = red[0] + red[2] + red[4] + red[6];
    float Q = red[1] + red[3] + red[5] + red[7];
    atomicAdd(&stats[bz * 2], S);
    atomicAdd(&stats[bz * 2 + 1], Q);
  }
}

// ---------------- K3: multi-CU sinkhorn, tagged-pair single-RT exchange ---------------------
// 8 blocks per batch, 320 thr (5 waves), 10 rows/wave, E fp32 in registers.
// Exchange: each published value is an 8B atom (tag<<32 | f32 bits) written with ONE 64-bit
// relaxed agent atomic -> tag and data land together (HW 8B atomicity). No fences, no flags:
// readers poll the atoms themselves until tag==it+1; the matched load IS the data.
// Parity double-buffer prevents ABA (block writes it+2 only after gathering all partners'
// it+1, which implies everyone consumed it). All 5 waves gather disjoint partner slices
// (wave wv: cc=wv and wv+5), own slice recomputed from LDS (identical bits, no self-RT).
// Fixed summation order everywhere -> Q bits identical across blocks -> uniform early-exit.
#define SBLK 8
#define SROWS 50
#define SRPW 10

__global__ __launch_bounds__(320, 1) void k_sinkhorn(const __half* __restrict__ sbuf,
                                                     const float* __restrict__ stats,
                                                     const float* __restrict__ gptr,
                                                     const float* __restrict__ bptr,
                                                     unsigned short* __restrict__ s1b,
                                                     ull* __restrict__ qpart) {
  __shared__ float qpl[5][320];   // per-wave own col partials
  __shared__ float qg[5][320];    // per-wave gathered cc-slice sums
  const int b = blockIdx.x, c = blockIdx.y;
  const int tid = threadIdx.x, wv = tid >> 6, l = tid & 63;
  const __half* S = sbuf + (size_t)b * NDIM * TPAD;
  unsigned short* S1 = s1b + (size_t)b * NDIM * TPAD;
  const float NT = 400.0f * 315.0f;
  const float mean = stats[2 * b] / NT;
  const float var = stats[2 * b + 1] / NT - mean * mean;
  const float inv = rsqrtf(var + 1e-5f);
  const float alpha = gptr[0] * inv;
  const float L2E = 1.4426950408889634f;
  const float a2 = alpha * L2E;
  const float d2 = (bptr[0] - mean * alpha) * L2E;
  const int r0 = c * SROWS + wv * SRPW;
  const float TOL = 1e-3f;
  const float TN_RATIO = 315.0f / 400.0f;

  // ---- prologue: E = exp(instnorm(s)) into registers, fp32, 5 cols/lane x 10 rows ----
  float E0[SRPW], E1[SRPW], E2[SRPW], E3[SRPW], E4[SRPW];
#pragma unroll
  for (int j = 0; j < SRPW; ++j) {
    const __half* row = S + (size_t)(r0 + j) * TPAD;
    E0[j] = __builtin_amdgcn_exp2f(fmaf(__half2float(row[l]), a2, d2));
    E1[j] = __builtin_amdgcn_exp2f(fmaf(__half2float(row[64 + l]), a2, d2));
    E2[j] = __builtin_amdgcn_exp2f(fmaf(__half2float(row[128 + l]), a2, d2));
    E3[j] = __builtin_amdgcn_exp2f(fmaf(__half2float(row[192 + l]), a2, d2));
    E4[j] = (l < 59) ? __builtin_amdgcn_exp2f(fmaf(__half2float(row[256 + l]), a2, d2)) : 0.0f;
  }
  float w0 = 1.0f, w1 = 1.0f, w2 = 1.0f, w3 = 1.0f, w4 = (l < 59) ? 1.0f : 0.0f;
  float aj[SRPW];
#pragma unroll
  for (int j = 0; j < SRPW; ++j) aj[j] = 0.0f;

  bool fin = false;
  for (int it = 0; it < NITER; ++it) {
    // ---- row sums p = E . w (registers only) ----
    float p[SRPW];
#pragma unroll
    for (int j = 0; j < SRPW; ++j) {
      float t = E4[j] * w4;
      t = fmaf(E3[j], w3, t);
      t = fmaf(E2[j], w2, t);
      t = fmaf(E1[j], w1, t);
      p[j] = fmaf(E0[j], w0, t);
    }
#pragma unroll
    for (int j = 0; j < SRPW; ++j) p[j] = dppadd<0x111, 0xf>(p[j]);
#pragma unroll
    for (int j = 0; j < SRPW; ++j) p[j] = dppadd<0x112, 0xf>(p[j]);
#pragma unroll
    for (int j = 0; j < SRPW; ++j) p[j] = dppadd<0x114, 0xf>(p[j]);
#pragma unroll
    for (int j = 0; j < SRPW; ++j) p[j] = dppadd<0x118, 0xf>(p[j]);
#pragma unroll
    for (int j = 0; j < SRPW; ++j) p[j] = dppadd<0x142, 0xa>(p[j]);
#pragma unroll
    for (int j = 0; j < SRPW; ++j) p[j] = dppadd<0x143, 0xc>(p[j]);
#pragma unroll
    for (int j = 0; j < SRPW; ++j) {
      float r = __builtin_amdgcn_rcpf(p[j]);
      aj[j] = __int_as_float(__builtin_amdgcn_readlane(__float_as_int(r), 63));
    }
    // ---- local col partials q = E^T . a ----
    float q0 = 0.f, q1 = 0.f, q2 = 0.f, q3 = 0.f, q4 = 0.f;
#pragma unroll
    for (int j = 0; j < SRPW; ++j) {
      q0 = fmaf(E0[j], aj[j], q0);
      q1 = fmaf(E1[j], aj[j], q1);
      q2 = fmaf(E2[j], aj[j], q2);
      q3 = fmaf(E3[j], aj[j], q3);
      q4 = fmaf(E4[j], aj[j], q4);
    }
    qpl[wv][l] = q0;
    qpl[wv][64 + l] = q1;
    qpl[wv][128 + l] = q2;
    qpl[wv][192 + l] = q3;
    qpl[wv][256 + l] = q4;
    __syncthreads();
    const int par = it & 1;
    const unsigned tgt = (unsigned)(it + 1);
    ull* bufpar = qpart + ((size_t)par * BDIM + b) * (SBLK * 320);
    // ---- publish own partial as tagged pairs (wave0) ----
    if (wv == 0) {
      ull* myp = bufpar + c * 320;
#pragma unroll
      for (int k = 0; k < 5; ++k) {
        int t = k * 64 + l;
        float sm = qpl[0][t] + qpl[1][t] + qpl[2][t] + qpl[3][t] + qpl[4][t];
        __hip_atomic_store(&myp[t], ((ull)tgt << 32) | (ull)__float_as_uint(sm),
                           __ATOMIC_RELAXED, __HIP_MEMORY_SCOPE_AGENT);
      }
    }
    // ---- gather: wave wv covers cc = wv and (wv+5 if wv<3); own cc from LDS ----
    {
      const int ncc = (wv < 3) ? 2 : 1;
      ull got[2][5];
      const int ccs[2] = {wv, wv + 5};
#pragma unroll
      for (int e = 0; e < 2; ++e)
        if (e < ncc && ccs[e] != c) {
#pragma unroll
          for (int k = 0; k < 5; ++k)
            got[e][k] = __hip_atomic_load(&bufpar[ccs[e] * 320 + k * 64 + l],
                                          __ATOMIC_RELAXED, __HIP_MEMORY_SCOPE_AGENT);
        }
      int guard = 0;
      for (;;) {
        bool ok = true;
#pragma unroll
        for (int e = 0; e < 2; ++e)
          if (e < ncc && ccs[e] != c) {
#pragma unroll
            for (int k = 0; k < 5; ++k)
              if ((unsigned)(got[e][k] >> 32) != tgt) {
                got[e][k] = __hip_atomic_load(&bufpar[ccs[e] * 320 + k * 64 + l],
                                              __ATOMIC_RELAXED, __HIP_MEMORY_SCOPE_AGENT);
                ok = false;
              }
          }
        if (ok) break;
        if (++guard > (1 << 20)) break;  // deadlock escape (should never trigger)
      }
      float part[5] = {0.f, 0.f, 0.f, 0.f, 0.f};
#pragma unroll
      for (int e = 0; e < 2; ++e)
        if (e < ncc) {
#pragma unroll
          for (int k = 0; k < 5; ++k) {
            int t = k * 64 + l;
            float v = (ccs[e] == c)
                          ? (qpl[0][t] + qpl[1][t] + qpl[2][t] + qpl[3][t] + qpl[4][t])
                          : __uint_as_float((unsigned)got[e][k]);
            part[k] += v;
          }
        }
#pragma unroll
      for (int k = 0; k < 5; ++k) qg[wv][k * 64 + l] = part[k];
    }
    __syncthreads();
    // ---- totals (fixed order (0+5)+(1+6)+(2+7)+3+4 -> identical bits in every block) ----
    const float Q0 = qg[0][l] + qg[1][l] + qg[2][l] + qg[3][l] + qg[4][l];
    const float Q1 = qg[0][64 + l] + qg[1][64 + l] + qg[2][64 + l] + qg[3][64 + l] + qg[4][64 + l];
    const float Q2 =
        qg[0][128 + l] + qg[1][128 + l] + qg[2][128 + l] + qg[3][128 + l] + qg[4][128 + l];
    const float Q3 =
        qg[0][192 + l] + qg[1][192 + l] + qg[2][192 + l] + qg[3][192 + l] + qg[4][192 + l];
    const float Q4 =
        qg[0][256 + l] + qg[1][256 + l] + qg[2][256 + l] + qg[3][256 + l] + qg[4][256 + l];
    // residual uses PRE-update w (matches previous kernel)
    float r = fabsf(fmaf(Q0 * w0, TN_RATIO, -1.0f));
    r = fmaxf(r, fabsf(fmaf(Q1 * w1, TN_RATIO, -1.0f)));
    r = fmaxf(r, fabsf(fmaf(Q2 * w2, TN_RATIO, -1.0f)));
    r = fmaxf(r, fabsf(fmaf(Q3 * w3, TN_RATIO, -1.0f)));
    if (l < 59) r = fmaxf(r, fabsf(fmaf(Q4 * w4, TN_RATIO, -1.0f)));
    w0 = __builtin_amdgcn_rcpf(Q0);
    w1 = __builtin_amdgcn_rcpf(Q1);
    w2 = __builtin_amdgcn_rcpf(Q2);
    w3 = __builtin_amdgcn_rcpf(Q3);
    if (l < 59) w4 = __builtin_amdgcn_rcpf(Q4);
    if (fin) break;  // fin iteration ends on the col-norm above, like the reference
    r = dppmax<0x111, 0xf>(r);
    r = dppmax<0x112, 0xf>(r);
    r = dppmax<0x114, 0xf>(r);
    r = dppmax<0x118, 0xf>(r);
    r = dppmax<0x142, 0xa>(r);
    r = dppmax<0x143, 0xc>(r);
    const float resid = __int_as_float(__builtin_amdgcn_readlane(__float_as_int(r), 63));
    fin = (resid < TOL) || (it == NITER - 2);
  }

  // ---- epilogue: s1 = a_fin * E * w_fin, written bf16 ----
#pragma unroll
  for (int j = 0; j < SRPW; ++j) {
    unsigned short* row = S1 + (size_t)(r0 + j) * TPAD;
    const float a = aj[j];
    row[l] = bf1(a * E0[j] * w0);
    row[64 + l] = bf1(a * E1[j] * w1);
    row[128 + l] = bf1(a * E2[j] * w2);
    row[192 + l] = bf1(a * E3[j] * w3);
    row[256 + l] = (l < 59) ? bf1(a * E4[j] * w4) : (unsigned short)0;
  }
}

// ---------------- K4: f1[b][t][d] = sum_n s1[b][n][t] * F[b][n][d]  (TN bf16 MFMA) ----------
__global__ __launch_bounds__(256) void k_f1(const unsigned short* __restrict__ s1b,
                                            const unsigned short* __restrict__ Fb,
                                            unsigned short* __restrict__ f1b) {
  __shared__ unsigned short Abf[64 * LDH];  // [t][n]
  __shared__ unsigned short Bbf[64 * LDH];  // [d][n]
  const int tid = threadIdx.x, l = tid & 63, wv = tid >> 6;
  const int d0 = blockIdx.x * 64, t0 = blockIdx.y * 64, bz = blockIdx.z;
  const unsigned short* sb = s1b + (size_t)bz * NDIM * TPAD;
  const unsigned short* Fbb = Fb + (size_t)bz * NDIM * DDIM;
  unsigned short* out = f1b + (size_t)bz * TDIM * DDIM;
  f32x4 acc[4] = {};
  const int col = tid & 31, g = tid >> 5;
  for (int k0 = 0; k0 < 416; k0 += 32) {
    int n = k0 + col;
    uint4 av = make_uint4(0, 0, 0, 0), bv = av;
    if (n < NDIM) {
      av = *(const uint4*)(sb + (size_t)n * TPAD + t0 + g * 8);
      bv = *(const uint4*)(Fbb + (size_t)n * DDIM + d0 + g * 8);
    }
    unsigned short ah[8], bh8[8];
    *(uint4*)ah = av;
    *(uint4*)bh8 = bv;
#pragma unroll
    for (int i = 0; i < 8; ++i) {
      Abf[(g * 8 + i) * LDH + col] = ah[i];
      Bbf[(g * 8 + i) * LDH + col] = bh8[i];
    }
    __syncthreads();
    bf16x8 af = *(const bf16x8*)(&Abf[(wv * 16 + (l & 15)) * LDH + (l >> 4) * 8]);
#pragma unroll
    for (int c = 0; c < 4; ++c) {
      bf16x8 bf_ = *(const bf16x8*)(&Bbf[(c * 16 + (l & 15)) * LDH + (l >> 4) * 8]);
      acc[c] = __builtin_amdgcn_mfma_f32_16x16x32_bf16(af, bf_, acc[c], 0, 0, 0);
    }
    __syncthreads();
  }
#pragma unroll
  for (int c = 0; c < 4; ++c)
#pragma unroll
    for (int r = 0; r < 4; ++r) {
      int t = t0 + wv * 16 + ((l >> 4) << 2) + r;
      int d = d0 + c * 16 + (l & 15);
      if (t < TDIM) out[(size_t)t * DDIM + d] = bf1(acc[c][r]);
    }
}

// ---------------- K5: fused h + pred (Wh pre-packed bf16) ----------------
__global__ __launch_bounds__(256) void k_hp(const unsigned short* __restrict__ f1b,
                                            const unsigned short* __restrict__ Whb,
                                            const float* __restrict__ TB,
                                            const float* __restrict__ Wo,
                                            const float* __restrict__ bo,
                                            float* __restrict__ out) {
  __shared__ unsigned short Abf[64 * LDH];  // [r][d]
  __shared__ unsigned short Bbf[64 * LDH];  // [j][d]
  __shared__ float Wos[64];
  const int tid = threadIdx.x, l = tid & 63, wv = tid >> 6;
  const int j0 = blockIdx.x * 64, r0 = blockIdx.y * 64;
  const int RTOT = BDIM * TDIM;  // 10080
  if (tid < 64) Wos[tid] = Wo[j0 + tid];
  f32x4 acc[4] = {};
  const int m = tid >> 2, kq = (tid & 3) * 8;
  const int col = tid & 31, g = tid >> 5;
  for (int k0 = 0; k0 < 512; k0 += 32) {
    uint4 av = make_uint4(0, 0, 0, 0);
    int r = r0 + m;
    if (r < RTOT) av = *(const uint4*)(f1b + (size_t)r * DDIM + k0 + kq);
    *(uint4*)(&Abf[m * LDH + kq]) = av;
    uint4 bv = *(const uint4*)(Whb + (size_t)(k0 + col) * HDIM + j0 + g * 8);
    unsigned short bh8[8];
    *(uint4*)bh8 = bv;
#pragma unroll
    for (int i = 0; i < 8; ++i) Bbf[(g * 8 + i) * LDH + col] = bh8[i];
    __syncthreads();
    bf16x8 af = *(const bf16x8*)(&Abf[(wv * 16 + (l & 15)) * LDH + (l >> 4) * 8]);
#pragma unroll
    for (int c = 0; c < 4; ++c) {
      bf16x8 bf_ = *(const bf16x8*)(&Bbf[(c * 16 + (l & 15)) * LDH + (l >> 4) * 8]);
      acc[c] = __builtin_amdgcn_mfma_f32_16x16x32_bf16(af, bf_, acc[c], 0, 0, 0);
    }
    __syncthreads();
  }
  int tmod[4];
#pragma unroll
  for (int r = 0; r < 4; ++r) {
    int rr = r0 + wv * 16 + ((l >> 4) << 2) + r;
    tmod[r] = rr % TDIM;
  }
  float part[4] = {0.f, 0.f, 0.f, 0.f};
#pragma unroll
  for (int c = 0; c < 4; ++c) {
    int jl = c * 16 + (l & 15);
    float woc = Wos[jl];
#pragma unroll
    for (int r = 0; r < 4; ++r) {
      float v = acc[c][r] + TB[(size_t)tmod[r] * HDIM + j0 + jl];
      part[r] = fmaf(fmaxf(v, 0.f), woc, part[r]);
    }
  }
#pragma unroll
  for (int r = 0; r < 4; ++r) part[r] = dppadd<0x111, 0xf>(part[r]);
#pragma unroll
  for (int r = 0; r < 4; ++r) part[r] = dppadd<0x112, 0xf>(part[r]);
#pragma unroll
  for (int r = 0; r < 4; ++r) part[r] = dppadd<0x114, 0xf>(part[r]);
#pragma unroll
  for (int r = 0; r < 4; ++r) part[r] = dppadd<0x118, 0xf>(part[r]);
  if ((l & 15) == 15) {
    float base = (j0 == 0) ? bo[0] : 0.0f;
#pragma unroll
    for (int r = 0; r < 4; ++r) {
      int rr = r0 + wv * 16 + ((l >> 4) << 2) + r;
      if (rr < RTOT) atomicAdd(&out[rr], part[r] + base);
    }
  }
}

// ---------------- launch ----------------
extern "C" void kernel_launch(void* const* d_in, const int* in_sizes, int n_in,
                              void* d_out, int out_size, void* d_ws, size_t ws_size,
                              hipStream_t stream) {
  const float* F     = (const float*)d_in[0];
  const float* text  = (const float*)d_in[1];
  const float* A     = (const float*)d_in[2];
  const float* gamma = (const float*)d_in[3];
  const float* beta  = (const float*)d_in[4];
  const float* Wh    = (const float*)d_in[5];
  const float* bh    = (const float*)d_in[6];
  const float* Wo    = (const float*)d_in[7];
  const float* bo    = (const float*)d_in[8];
  float* out = (float*)d_out;
  char* ws = (char*)d_ws;
  unsigned short* tAb = (unsigned short*)(ws + OFS_TAB);
  float* TB    = (float*)(ws + OFS_TB);
  float* stats = (float*)(ws + OFS_STATS);
  unsigned short* Whb = (unsigned short*)(ws + OFS_WHB);
  __half* sbuf = (__half*)(ws + OFS_S);
  unsigned short* s1b = (unsigned short*)(ws + OFS_S1B);
  unsigned short* f1b = (unsigned short*)(ws + OFS_F1);
  unsigned short* Fb  = (unsigned short*)(ws + OFS_FB);
  ull* qpart = (ull*)(ws + OFS_QPART);

  k_pack<<<512, 256, 0, stream>>>(F, Wh, Fb, Whb, out, out_size, stats, (uint4*)qpart);
  k_pre<<<dim3(8, 5, 2), 256, 0, stream>>>(text, A, Wh, bh, tAb, TB);
  k_s<<<dim3(5, 7, 32), 256, 0, stream>>>(Fb, tAb, sbuf, stats);
  k_sinkhorn<<<dim3(BDIM, SBLK), 320, 0, stream>>>(sbuf, stats, gamma, beta, s1b, qpart);
  k_f1<<<dim3(8, 5, 32), 256, 0, stream>>>(s1b, Fb, f1b);
  k_hp<<<dim3(4, 158), 256, 0, stream>>>(f1b, Whb, TB, Wo, bo, out);
}

// Round 4
// 188.364 us; speedup vs baseline: 1.5056x; 1.1382x over previous
//
#include <hip/hip_runtime.h>
#include <hip/hip_fp16.h>

// Problem dims
#define BDIM 32
#define NDIM 400
#define TDIM 315
#define TPAD 320
#define DDIM 512
#define HDIM 256
#define NITER 100

// Workspace layout (bytes), tightly packed (~41 MB)
#define OFS_TAB   0u          // tAb bf16 [320][512] = 327680
#define OFS_TB    327680u     // TB f32 [320][256] = 327680
#define OFS_STATS 655360u     // stats[32][2] f32 = 256
#define OFS_WHB   655616u     // Whb bf16 [512][256] = 262144
#define OFS_S     1048576u    // s fp16 [32][400][320] = 8192000
#define OFS_S1B   9240576u    // s1b bf16 [32][400][320] = 8192000
#define OFS_F1    17432576u   // f1b bf16 [32][315][512] = 10321920  (end 27754496)
#define OFS_FB    27754496u   // Fb bf16 [32][400][512] = 13107200  (end 40861696)
// k_pre hi/lo packs overlap the s1b region (s1b is written AFTER k_pre, by k_sinkhorn):
#define OFS_THL   OFS_S1B             // text hi/lo us [2][320][512] = 655360
#define OFS_AHL   (OFS_S1B + 655360u) // A hi/lo us [2][512][512] = 1048576
#define OFS_WHL   (OFS_S1B + 1703936u)// Wh_bot hi/lo us [2][512][256] = 524288 (end S1B+2228224)
// k_sinkhorn scratch overlaps the f1b region (f1b is produced AFTER sinkhorn):
// qpart: tagged pairs (u32 tag | f32 data) [2 parity][32 b][8 c][320] ull = 1310720 B
#define OFS_QPART (OFS_F1 + 4096u)

typedef __attribute__((ext_vector_type(8))) short bf16x8;
typedef __attribute__((ext_vector_type(4))) float f32x4;
typedef unsigned long long ull;

// ---------------- bf16 pack/unpack (RNE) ----------------
__device__ __forceinline__ unsigned rne_hi(float x) {
  unsigned u = __float_as_uint(x);
  u += 0x7fffu + ((u >> 16) & 1u);
  return u & 0xffff0000u;
}
__device__ __forceinline__ unsigned pack2(float lo, float hi) {
  return (rne_hi(lo) >> 16) | rne_hi(hi);
}
__device__ __forceinline__ unsigned short bf1(float x) { return (unsigned short)(rne_hi(x) >> 16); }
__device__ __forceinline__ float bfres(float x) {  // x - bf16(x), the lo part
  return x - __uint_as_float(rne_hi(x));
}

// ---------------- DPP wave reduce helpers (VALU pipe, no LDS) ----------------
template <int CTRL, int RMASK>
__device__ __forceinline__ float dppadd(float x) {
  int y = __builtin_amdgcn_update_dpp(0, __float_as_int(x), CTRL, RMASK, 0xf, true);
  return x + __int_as_float(y);
}
template <int CTRL, int RMASK>
__device__ __forceinline__ float dppmax(float x) {
  int y = __builtin_amdgcn_update_dpp(0, __float_as_int(x), CTRL, RMASK, 0xf, true);
  return fmaxf(x, __int_as_float(y));
}

// ---------------- K0: bf16 packing (F, Wh_top, hi/lo of text/A/Wh_bot) + zero-init ---------
__global__ void k_pack(const float* __restrict__ F, const float* __restrict__ Wh,
                       const float* __restrict__ text, const float* __restrict__ A,
                       unsigned short* __restrict__ Fb, unsigned short* __restrict__ Whb,
                       unsigned short* __restrict__ tHL, unsigned short* __restrict__ aHL,
                       unsigned short* __restrict__ wHL,
                       float* __restrict__ out, int out_n, float* __restrict__ stats,
                       uint4* __restrict__ qzero) {
  const int NF4 = (BDIM * NDIM * DDIM) / 4;      // 1638400
  const int NW4 = (DDIM * HDIM) / 4;             // 32768 (top half of Wh)
  const int NT4 = (TPAD * DDIM) / 4;             // 40960 (padded text)
  const int NTS4 = (TDIM * DDIM) / 4;            // 40320 (source text float4s)
  const int NA4 = (DDIM * DDIM) / 4;             // 65536
  const int NWB4 = (DDIM * HDIM) / 4;            // 32768 (bottom half of Wh)
  const int NQ4 = (2 * BDIM * 8 * 320 * 2) / 4;  // qpart u32 count / 4 = 81920
  int tid0 = blockIdx.x * blockDim.x + threadIdx.x;
  int stride = gridDim.x * blockDim.x;
  for (int i = tid0; i < NF4; i += stride) {
    float4 v = ((const float4*)F)[i];
    ((uint2*)Fb)[i] = make_uint2(pack2(v.x, v.y), pack2(v.z, v.w));
  }
  for (int i = tid0; i < NW4; i += stride) {
    float4 v = ((const float4*)Wh)[i];
    ((uint2*)Whb)[i] = make_uint2(pack2(v.x, v.y), pack2(v.z, v.w));
  }
  // text hi/lo, zero-padded to 320 rows
  for (int i = tid0; i < NT4; i += stride) {
    float4 v = make_float4(0.f, 0.f, 0.f, 0.f);
    if (i < NTS4) v = ((const float4*)text)[i];
    ((uint2*)tHL)[i] = make_uint2(pack2(v.x, v.y), pack2(v.z, v.w));
    ((uint2*)(tHL + TPAD * DDIM))[i] =
        make_uint2(pack2(bfres(v.x), bfres(v.y)), pack2(bfres(v.z), bfres(v.w)));
  }
  // A hi/lo
  for (int i = tid0; i < NA4; i += stride) {
    float4 v = ((const float4*)A)[i];
    ((uint2*)aHL)[i] = make_uint2(pack2(v.x, v.y), pack2(v.z, v.w));
    ((uint2*)(aHL + DDIM * DDIM))[i] =
        make_uint2(pack2(bfres(v.x), bfres(v.y)), pack2(bfres(v.z), bfres(v.w)));
  }
  // Wh bottom hi/lo (layout kept [k][h])
  const float* Wb = Wh + DDIM * HDIM;
  for (int i = tid0; i < NWB4; i += stride) {
    float4 v = ((const float4*)Wb)[i];
    ((uint2*)wHL)[i] = make_uint2(pack2(v.x, v.y), pack2(v.z, v.w));
    ((uint2*)(wHL + DDIM * HDIM))[i] =
        make_uint2(pack2(bfres(v.x), bfres(v.y)), pack2(bfres(v.z), bfres(v.w)));
  }
  for (int i = tid0; i < out_n; i += stride) out[i] = 0.0f;
  for (int i = tid0; i < NQ4; i += stride) qzero[i] = make_uint4(0u, 0u, 0u, 0u);
  if (tid0 < BDIM * 2) stats[tid0] = 0.0f;
}

// ================= MFMA GEMMs: 64x64 tile, 256 thr (4 waves), 16x16x32 bf16 =================
#define LDH 40

// ---------------- K1: tA (z=0) + TB (z=1) via bf16x3 split MFMA (~fp32 accuracy) ------------
// x = hi + lo (hi=bf16(x), lo=bf16(x-hi)); acc += hi*hi + hi*lo + lo*hi; dropped lo*lo ~2^-18.
__global__ __launch_bounds__(256) void k_pre(const unsigned short* __restrict__ tHL,
                                             const unsigned short* __restrict__ aHL,
                                             const unsigned short* __restrict__ wHL,
                                             const float* __restrict__ bh,
                                             unsigned short* __restrict__ tAb,
                                             float* __restrict__ TB) {
  __shared__ unsigned short Ahs[64 * LDH], Als[64 * LDH];
  __shared__ unsigned short Bhs[64 * LDH], Bls[64 * LDH];
  const int tid = threadIdx.x, l = tid & 63, wv = tid >> 6;
  const int m = tid >> 2, kq = (tid & 3) * 8;
  const int t0 = blockIdx.y * 64;
  const unsigned short* tH = tHL;                 // [320][512]
  const unsigned short* tL = tHL + TPAD * DDIM;
  f32x4 acc[4] = {};
  if (blockIdx.z == 0) {
    const int d0 = blockIdx.x * 64;
    const unsigned short* AH = aHL;               // [512][512]
    const unsigned short* AL = aHL + DDIM * DDIM;
    for (int k0 = 0; k0 < 512; k0 += 32) {
      *(uint4*)(&Ahs[m * LDH + kq]) = *(const uint4*)(tH + (size_t)(t0 + m) * DDIM + k0 + kq);
      *(uint4*)(&Als[m * LDH + kq]) = *(const uint4*)(tL + (size_t)(t0 + m) * DDIM + k0 + kq);
      *(uint4*)(&Bhs[m * LDH + kq]) = *(const uint4*)(AH + (size_t)(d0 + m) * DDIM + k0 + kq);
      *(uint4*)(&Bls[m * LDH + kq]) = *(const uint4*)(AL + (size_t)(d0 + m) * DDIM + k0 + kq);
      __syncthreads();
      bf16x8 ah = *(const bf16x8*)(&Ahs[(wv * 16 + (l & 15)) * LDH + (l >> 4) * 8]);
      bf16x8 al = *(const bf16x8*)(&Als[(wv * 16 + (l & 15)) * LDH + (l >> 4) * 8]);
#pragma unroll
      for (int c = 0; c < 4; ++c) {
        bf16x8 bh_ = *(const bf16x8*)(&Bhs[(c * 16 + (l & 15)) * LDH + (l >> 4) * 8]);
        bf16x8 bl_ = *(const bf16x8*)(&Bls[(c * 16 + (l & 15)) * LDH + (l >> 4) * 8]);
        acc[c] = __builtin_amdgcn_mfma_f32_16x16x32_bf16(ah, bh_, acc[c], 0, 0, 0);
        acc[c] = __builtin_amdgcn_mfma_f32_16x16x32_bf16(ah, bl_, acc[c], 0, 0, 0);
        acc[c] = __builtin_amdgcn_mfma_f32_16x16x32_bf16(al, bh_, acc[c], 0, 0, 0);
      }
      __syncthreads();
    }
#pragma unroll
    for (int c = 0; c < 4; ++c)
#pragma unroll
      for (int r = 0; r < 4; ++r) {
        int t = t0 + wv * 16 + ((l >> 4) << 2) + r;  // pad rows (>=315) are exact zeros
        int d = d0 + c * 16 + (l & 15);
        tAb[(size_t)t * DDIM + d] = bf1(acc[c][r]);
      }
  } else {
    if (blockIdx.x >= 4) return;
    const int h0 = blockIdx.x * 64;
    const unsigned short* WH = wHL;               // [512][256] (k-major)
    const unsigned short* WL = wHL + DDIM * HDIM;
    const int col = tid & 31, g = tid >> 5;
    for (int k0 = 0; k0 < 512; k0 += 32) {
      *(uint4*)(&Ahs[m * LDH + kq]) = *(const uint4*)(tH + (size_t)(t0 + m) * DDIM + k0 + kq);
      *(uint4*)(&Als[m * LDH + kq]) = *(const uint4*)(tL + (size_t)(t0 + m) * DDIM + k0 + kq);
      uint4 wh4 = *(const uint4*)(WH + (size_t)(k0 + col) * HDIM + h0 + g * 8);
      uint4 wl4 = *(const uint4*)(WL + (size_t)(k0 + col) * HDIM + h0 + g * 8);
      unsigned short wh8[8], wl8[8];
      *(uint4*)wh8 = wh4;
      *(uint4*)wl8 = wl4;
#pragma unroll
      for (int i = 0; i < 8; ++i) {
        Bhs[(g * 8 + i) * LDH + col] = wh8[i];
        Bls[(g * 8 + i) * LDH + col] = wl8[i];
      }
      __syncthreads();
      bf16x8 ah = *(const bf16x8*)(&Ahs[(wv * 16 + (l & 15)) * LDH + (l >> 4) * 8]);
      bf16x8 al = *(const bf16x8*)(&Als[(wv * 16 + (l & 15)) * LDH + (l >> 4) * 8]);
#pragma unroll
      for (int c = 0; c < 4; ++c) {
        bf16x8 bh_ = *(const bf16x8*)(&Bhs[(c * 16 + (l & 15)) * LDH + (l >> 4) * 8]);
        bf16x8 bl_ = *(const bf16x8*)(&Bls[(c * 16 + (l & 15)) * LDH + (l >> 4) * 8]);
        acc[c] = __builtin_amdgcn_mfma_f32_16x16x32_bf16(ah, bh_, acc[c], 0, 0, 0);
        acc[c] = __builtin_amdgcn_mfma_f32_16x16x32_bf16(ah, bl_, acc[c], 0, 0, 0);
        acc[c] = __builtin_amdgcn_mfma_f32_16x16x32_bf16(al, bh_, acc[c], 0, 0, 0);
      }
      __syncthreads();
    }
#pragma unroll
    for (int c = 0; c < 4; ++c)
#pragma unroll
      for (int r = 0; r < 4; ++r) {
        int t = t0 + wv * 16 + ((l >> 4) << 2) + r;
        int h = h0 + c * 16 + (l & 15);
        TB[(size_t)t * HDIM + h] = acc[c][r] + bh[h];
      }
  }
}

// ---------------- K2: s[b][n][t] (fp16 out) + instnorm stats; operands pre-packed bf16 ------
__global__ __launch_bounds__(256) void k_s(const unsigned short* __restrict__ Fb,
                                           const unsigned short* __restrict__ tAb,
                                           __half* __restrict__ s, float* __restrict__ stats) {
  __shared__ unsigned short Abf[64 * LDH];
  __shared__ unsigned short Bbf[64 * LDH];
  __shared__ float red[8];
  const int tid = threadIdx.x, l = tid & 63, wv = tid >> 6;
  const int t0 = blockIdx.x * 64, n0 = blockIdx.y * 64, bz = blockIdx.z;
  const unsigned short* Fbb = Fb + (size_t)bz * NDIM * DDIM;
  __half* sb = s + (size_t)bz * NDIM * TPAD;
  f32x4 acc[4] = {};
  const int m = tid >> 2, kq = (tid & 3) * 8;
  for (int k0 = 0; k0 < 512; k0 += 32) {
    uint4 av = make_uint4(0, 0, 0, 0);
    int n = n0 + m;
    if (n < NDIM) av = *(const uint4*)(Fbb + (size_t)n * DDIM + k0 + kq);
    *(uint4*)(&Abf[m * LDH + kq]) = av;
    uint4 bv = *(const uint4*)(tAb + (size_t)(t0 + m) * DDIM + k0 + kq);
    *(uint4*)(&Bbf[m * LDH + kq]) = bv;
    __syncthreads();
    bf16x8 af = *(const bf16x8*)(&Abf[(wv * 16 + (l & 15)) * LDH + (l >> 4) * 8]);
#pragma unroll
    for (int c = 0; c < 4; ++c) {
      bf16x8 bf_ = *(const bf16x8*)(&Bbf[(c * 16 + (l & 15)) * LDH + (l >> 4) * 8]);
      acc[c] = __builtin_amdgcn_mfma_f32_16x16x32_bf16(af, bf_, acc[c], 0, 0, 0);
    }
    __syncthreads();
  }
  float lsum = 0.f, lsq = 0.f;
#pragma unroll
  for (int c = 0; c < 4; ++c)
#pragma unroll
    for (int r = 0; r < 4; ++r) {
      int n = n0 + wv * 16 + ((l >> 4) << 2) + r;
      int t = t0 + c * 16 + (l & 15);
      if (n < NDIM && t < TDIM) {
        float v = acc[c][r];
        sb[(size_t)n * TPAD + t] = __float2half(v);
        lsum += v;
        lsq = fmaf(v, v, lsq);
      }
    }
#pragma unroll
  for (int mm = 1; mm <= 32; mm <<= 1) {
    lsum += __shfl_xor(lsum, mm, 64);
    lsq += __shfl_xor(lsq, mm, 64);
  }
  if ((tid & 63) == 0) { red[wv * 2] = lsum; red[wv * 2 + 1] = lsq; }
  __syncthreads();
  if (tid == 0) {
    float S = red[0] + red[2] + red[4] + red[6];
    float Q = red[1] + red[3] + red[5] + red[7];
    atomicAdd(&stats[bz * 2], S);
    atomicAdd(&stats[bz * 2 + 1], Q);
  }
}

// ---------------- K3: multi-CU sinkhorn, tagged-pair single-RT exchange ---------------------
// 8 blocks per batch, 320 thr (5 waves), 10 rows/wave, E fp32 in registers.
// Exchange: each published value is an 8B atom (tag<<32 | f32 bits) written with ONE 64-bit
// relaxed agent atomic -> tag and data land together (HW 8B atomicity). No fences, no flags:
// readers poll the atoms themselves until tag==it+1; the matched load IS the data.
// Parity double-buffer prevents ABA. All 5 waves gather disjoint partner slices; own slice
// recomputed from LDS. Fixed summation order -> identical bits -> uniform early-exit.
#define SBLK 8
#define SROWS 50
#define SRPW 10

__global__ __launch_bounds__(320, 1) void k_sinkhorn(const __half* __restrict__ sbuf,
                                                     const float* __restrict__ stats,
                                                     const float* __restrict__ gptr,
                                                     const float* __restrict__ bptr,
                                                     unsigned short* __restrict__ s1b,
                                                     ull* __restrict__ qpart) {
  __shared__ float qpl[5][320];   // per-wave own col partials
  __shared__ float qg[5][320];    // per-wave gathered cc-slice sums
  const int b = blockIdx.x, c = blockIdx.y;
  const int tid = threadIdx.x, wv = tid >> 6, l = tid & 63;
  const __half* S = sbuf + (size_t)b * NDIM * TPAD;
  unsigned short* S1 = s1b + (size_t)b * NDIM * TPAD;
  const float NT = 400.0f * 315.0f;
  const float mean = stats[2 * b] / NT;
  const float var = stats[2 * b + 1] / NT - mean * mean;
  const float inv = rsqrtf(var + 1e-5f);
  const float alpha = gptr[0] * inv;
  const float L2E = 1.4426950408889634f;
  const float a2 = alpha * L2E;
  const float d2 = (bptr[0] - mean * alpha) * L2E;
  const int r0 = c * SROWS + wv * SRPW;
  const float TOL = 1e-3f;
  const float TN_RATIO = 315.0f / 400.0f;

  // ---- prologue: E = exp(instnorm(s)) into registers, fp32, 5 cols/lane x 10 rows ----
  float E0[SRPW], E1[SRPW], E2[SRPW], E3[SRPW], E4[SRPW];
#pragma unroll
  for (int j = 0; j < SRPW; ++j) {
    const __half* row = S + (size_t)(r0 + j) * TPAD;
    E0[j] = __builtin_amdgcn_exp2f(fmaf(__half2float(row[l]), a2, d2));
    E1[j] = __builtin_amdgcn_exp2f(fmaf(__half2float(row[64 + l]), a2, d2));
    E2[j] = __builtin_amdgcn_exp2f(fmaf(__half2float(row[128 + l]), a2, d2));
    E3[j] = __builtin_amdgcn_exp2f(fmaf(__half2float(row[192 + l]), a2, d2));
    E4[j] = (l < 59) ? __builtin_amdgcn_exp2f(fmaf(__half2float(row[256 + l]), a2, d2)) : 0.0f;
  }
  float w0 = 1.0f, w1 = 1.0f, w2 = 1.0f, w3 = 1.0f, w4 = (l < 59) ? 1.0f : 0.0f;
  float aj[SRPW];
#pragma unroll
  for (int j = 0; j < SRPW; ++j) aj[j] = 0.0f;

  bool fin = false;
  for (int it = 0; it < NITER; ++it) {
    // ---- row sums p = E . w (registers only) ----
    float p[SRPW];
#pragma unroll
    for (int j = 0; j < SRPW; ++j) {
      float t = E4[j] * w4;
      t = fmaf(E3[j], w3, t);
      t = fmaf(E2[j], w2, t);
      t = fmaf(E1[j], w1, t);
      p[j] = fmaf(E0[j], w0, t);
    }
#pragma unroll
    for (int j = 0; j < SRPW; ++j) p[j] = dppadd<0x111, 0xf>(p[j]);
#pragma unroll
    for (int j = 0; j < SRPW; ++j) p[j] = dppadd<0x112, 0xf>(p[j]);
#pragma unroll
    for (int j = 0; j < SRPW; ++j) p[j] = dppadd<0x114, 0xf>(p[j]);
#pragma unroll
    for (int j = 0; j < SRPW; ++j) p[j] = dppadd<0x118, 0xf>(p[j]);
#pragma unroll
    for (int j = 0; j < SRPW; ++j) p[j] = dppadd<0x142, 0xa>(p[j]);
#pragma unroll
    for (int j = 0; j < SRPW; ++j) p[j] = dppadd<0x143, 0xc>(p[j]);
#pragma unroll
    for (int j = 0; j < SRPW; ++j) {
      float r = __builtin_amdgcn_rcpf(p[j]);
      aj[j] = __int_as_float(__builtin_amdgcn_readlane(__float_as_int(r), 63));
    }
    // ---- local col partials q = E^T . a ----
    float q0 = 0.f, q1 = 0.f, q2 = 0.f, q3 = 0.f, q4 = 0.f;
#pragma unroll
    for (int j = 0; j < SRPW; ++j) {
      q0 = fmaf(E0[j], aj[j], q0);
      q1 = fmaf(E1[j], aj[j], q1);
      q2 = fmaf(E2[j], aj[j], q2);
      q3 = fmaf(E3[j], aj[j], q3);
      q4 = fmaf(E4[j], aj[j], q4);
    }
    qpl[wv][l] = q0;
    qpl[wv][64 + l] = q1;
    qpl[wv][128 + l] = q2;
    qpl[wv][192 + l] = q3;
    qpl[wv][256 + l] = q4;
    __syncthreads();
    const int par = it & 1;
    const unsigned tgt = (unsigned)(it + 1);
    ull* bufpar = qpart + ((size_t)par * BDIM + b) * (SBLK * 320);
    // ---- publish own partial as tagged pairs (wave0) ----
    if (wv == 0) {
      ull* myp = bufpar + c * 320;
#pragma unroll
      for (int k = 0; k < 5; ++k) {
        int t = k * 64 + l;
        float sm = qpl[0][t] + qpl[1][t] + qpl[2][t] + qpl[3][t] + qpl[4][t];
        __hip_atomic_store(&myp[t], ((ull)tgt << 32) | (ull)__float_as_uint(sm),
                           __ATOMIC_RELAXED, __HIP_MEMORY_SCOPE_AGENT);
      }
    }
    // ---- gather: wave wv covers cc = wv and (wv+5 if wv<3); own cc from LDS ----
    {
      const int ncc = (wv < 3) ? 2 : 1;
      ull got[2][5];
      const int ccs[2] = {wv, wv + 5};
#pragma unroll
      for (int e = 0; e < 2; ++e)
        if (e < ncc && ccs[e] != c) {
#pragma unroll
          for (int k = 0; k < 5; ++k)
            got[e][k] = __hip_atomic_load(&bufpar[ccs[e] * 320 + k * 64 + l],
                                          __ATOMIC_RELAXED, __HIP_MEMORY_SCOPE_AGENT);
        }
      int guard = 0;
      for (;;) {
        bool ok = true;
#pragma unroll
        for (int e = 0; e < 2; ++e)
          if (e < ncc && ccs[e] != c) {
#pragma unroll
            for (int k = 0; k < 5; ++k)
              if ((unsigned)(got[e][k] >> 32) != tgt) {
                got[e][k] = __hip_atomic_load(&bufpar[ccs[e] * 320 + k * 64 + l],
                                              __ATOMIC_RELAXED, __HIP_MEMORY_SCOPE_AGENT);
                ok = false;
              }
          }
        if (ok) break;
        if (++guard > (1 << 20)) break;  // deadlock escape (should never trigger)
      }
      float part[5] = {0.f, 0.f, 0.f, 0.f, 0.f};
#pragma unroll
      for (int e = 0; e < 2; ++e)
        if (e < ncc) {
#pragma unroll
          for (int k = 0; k < 5; ++k) {
            int t = k * 64 + l;
            float v = (ccs[e] == c)
                          ? (qpl[0][t] + qpl[1][t] + qpl[2][t] + qpl[3][t] + qpl[4][t])
                          : __uint_as_float((unsigned)got[e][k]);
            part[k] += v;
          }
        }
#pragma unroll
      for (int k = 0; k < 5; ++k) qg[wv][k * 64 + l] = part[k];
    }
    __syncthreads();
    // ---- totals (fixed order (0+5)+(1+6)+(2+7)+3+4 -> identical bits in every block) ----
    const float Q0 = qg[0][l] + qg[1][l] + qg[2][l] + qg[3][l] + qg[4][l];
    const float Q1 = qg[0][64 + l] + qg[1][64 + l] + qg[2][64 + l] + qg[3][64 + l] + qg[4][64 + l];
    const float Q2 =
        qg[0][128 + l] + qg[1][128 + l] + qg[2][128 + l] + qg[3][128 + l] + qg[4][128 + l];
    const float Q3 =
        qg[0][192 + l] + qg[1][192 + l] + qg[2][192 + l] + qg[3][192 + l] + qg[4][192 + l];
    const float Q4 =
        qg[0][256 + l] + qg[1][256 + l] + qg[2][256 + l] + qg[3][256 + l] + qg[4][256 + l];
    // residual uses PRE-update w (matches previous kernel)
    float r = fabsf(fmaf(Q0 * w0, TN_RATIO, -1.0f));
    r = fmaxf(r, fabsf(fmaf(Q1 * w1, TN_RATIO, -1.0f)));
    r = fmaxf(r, fabsf(fmaf(Q2 * w2, TN_RATIO, -1.0f)));
    r = fmaxf(r, fabsf(fmaf(Q3 * w3, TN_RATIO, -1.0f)));
    if (l < 59) r = fmaxf(r, fabsf(fmaf(Q4 * w4, TN_RATIO, -1.0f)));
    w0 = __builtin_amdgcn_rcpf(Q0);
    w1 = __builtin_amdgcn_rcpf(Q1);
    w2 = __builtin_amdgcn_rcpf(Q2);
    w3 = __builtin_amdgcn_rcpf(Q3);
    if (l < 59) w4 = __builtin_amdgcn_rcpf(Q4);
    if (fin) break;  // fin iteration ends on the col-norm above, like the reference
    r = dppmax<0x111, 0xf>(r);
    r = dppmax<0x112, 0xf>(r);
    r = dppmax<0x114, 0xf>(r);
    r = dppmax<0x118, 0xf>(r);
    r = dppmax<0x142, 0xa>(r);
    r = dppmax<0x143, 0xc>(r);
    const float resid = __int_as_float(__builtin_amdgcn_readlane(__float_as_int(r), 63));
    fin = (resid < TOL) || (it == NITER - 2);
  }

  // ---- epilogue: s1 = a_fin * E * w_fin, written bf16 ----
#pragma unroll
  for (int j = 0; j < SRPW; ++j) {
    unsigned short* row = S1 + (size_t)(r0 + j) * TPAD;
    const float a = aj[j];
    row[l] = bf1(a * E0[j] * w0);
    row[64 + l] = bf1(a * E1[j] * w1);
    row[128 + l] = bf1(a * E2[j] * w2);
    row[192 + l] = bf1(a * E3[j] * w3);
    row[256 + l] = (l < 59) ? bf1(a * E4[j] * w4) : (unsigned short)0;
  }
}

// ---------------- K4: f1[b][t][d] = sum_n s1[b][n][t] * F[b][n][d]  (TN bf16 MFMA) ----------
__global__ __launch_bounds__(256) void k_f1(const unsigned short* __restrict__ s1b,
                                            const unsigned short* __restrict__ Fb,
                                            unsigned short* __restrict__ f1b) {
  __shared__ unsigned short Abf[64 * LDH];  // [t][n]
  __shared__ unsigned short Bbf[64 * LDH];  // [d][n]
  const int tid = threadIdx.x, l = tid & 63, wv = tid >> 6;
  const int d0 = blockIdx.x * 64, t0 = blockIdx.y * 64, bz = blockIdx.z;
  const unsigned short* sb = s1b + (size_t)bz * NDIM * TPAD;
  const unsigned short* Fbb = Fb + (size_t)bz * NDIM * DDIM;
  unsigned short* out = f1b + (size_t)bz * TDIM * DDIM;
  f32x4 acc[4] = {};
  const int col = tid & 31, g = tid >> 5;
  for (int k0 = 0; k0 < 416; k0 += 32) {
    int n = k0 + col;
    uint4 av = make_uint4(0, 0, 0, 0), bv = av;
    if (n < NDIM) {
      av = *(const uint4*)(sb + (size_t)n * TPAD + t0 + g * 8);
      bv = *(const uint4*)(Fbb + (size_t)n * DDIM + d0 + g * 8);
    }
    unsigned short ah[8], bh8[8];
    *(uint4*)ah = av;
    *(uint4*)bh8 = bv;
#pragma unroll
    for (int i = 0; i < 8; ++i) {
      Abf[(g * 8 + i) * LDH + col] = ah[i];
      Bbf[(g * 8 + i) * LDH + col] = bh8[i];
    }
    __syncthreads();
    bf16x8 af = *(const bf16x8*)(&Abf[(wv * 16 + (l & 15)) * LDH + (l >> 4) * 8]);
#pragma unroll
    for (int c = 0; c < 4; ++c) {
      bf16x8 bf_ = *(const bf16x8*)(&Bbf[(c * 16 + (l & 15)) * LDH + (l >> 4) * 8]);
      acc[c] = __builtin_amdgcn_mfma_f32_16x16x32_bf16(af, bf_, acc[c], 0, 0, 0);
    }
    __syncthreads();
  }
#pragma unroll
  for (int c = 0; c < 4; ++c)
#pragma unroll
    for (int r = 0; r < 4; ++r) {
      int t = t0 + wv * 16 + ((l >> 4) << 2) + r;
      int d = d0 + c * 16 + (l & 15);
      if (t < TDIM) out[(size_t)t * DDIM + d] = bf1(acc[c][r]);
    }
}

// ---------------- K5: fused h + pred (Wh pre-packed bf16) ----------------
__global__ __launch_bounds__(256) void k_hp(const unsigned short* __restrict__ f1b,
                                            const unsigned short* __restrict__ Whb,
                                            const float* __restrict__ TB,
                                            const float* __restrict__ Wo,
                                            const float* __restrict__ bo,
                                            float* __restrict__ out) {
  __shared__ unsigned short Abf[64 * LDH];  // [r][d]
  __shared__ unsigned short Bbf[64 * LDH];  // [j][d]
  __shared__ float Wos[64];
  const int tid = threadIdx.x, l = tid & 63, wv = tid >> 6;
  const int j0 = blockIdx.x * 64, r0 = blockIdx.y * 64;
  const int RTOT = BDIM * TDIM;  // 10080
  if (tid < 64) Wos[tid] = Wo[j0 + tid];
  f32x4 acc[4] = {};
  const int m = tid >> 2, kq = (tid & 3) * 8;
  const int col = tid & 31, g = tid >> 5;
  for (int k0 = 0; k0 < 512; k0 += 32) {
    uint4 av = make_uint4(0, 0, 0, 0);
    int r = r0 + m;
    if (r < RTOT) av = *(const uint4*)(f1b + (size_t)r * DDIM + k0 + kq);
    *(uint4*)(&Abf[m * LDH + kq]) = av;
    uint4 bv = *(const uint4*)(Whb + (size_t)(k0 + col) * HDIM + j0 + g * 8);
    unsigned short bh8[8];
    *(uint4*)bh8 = bv;
#pragma unroll
    for (int i = 0; i < 8; ++i) Bbf[(g * 8 + i) * LDH + col] = bh8[i];
    __syncthreads();
    bf16x8 af = *(const bf16x8*)(&Abf[(wv * 16 + (l & 15)) * LDH + (l >> 4) * 8]);
#pragma unroll
    for (int c = 0; c < 4; ++c) {
      bf16x8 bf_ = *(const bf16x8*)(&Bbf[(c * 16 + (l & 15)) * LDH + (l >> 4) * 8]);
      acc[c] = __builtin_amdgcn_mfma_f32_16x16x32_bf16(af, bf_, acc[c], 0, 0, 0);
    }
    __syncthreads();
  }
  int tmod[4];
#pragma unroll
  for (int r = 0; r < 4; ++r) {
    int rr = r0 + wv * 16 + ((l >> 4) << 2) + r;
    tmod[r] = rr % TDIM;
  }
  float part[4] = {0.f, 0.f, 0.f, 0.f};
#pragma unroll
  for (int c = 0; c < 4; ++c) {
    int jl = c * 16 + (l & 15);
    float woc = Wos[jl];
#pragma unroll
    for (int r = 0; r < 4; ++r) {
      float v = acc[c][r] + TB[(size_t)tmod[r] * HDIM + j0 + jl];
      part[r] = fmaf(fmaxf(v, 0.f), woc, part[r]);
    }
  }
#pragma unroll
  for (int r = 0; r < 4; ++r) part[r] = dppadd<0x111, 0xf>(part[r]);
#pragma unroll
  for (int r = 0; r < 4; ++r) part[r] = dppadd<0x112, 0xf>(part[r]);
#pragma unroll
  for (int r = 0; r < 4; ++r) part[r] = dppadd<0x114, 0xf>(part[r]);
#pragma unroll
  for (int r = 0; r < 4; ++r) part[r] = dppadd<0x118, 0xf>(part[r]);
  if ((l & 15) == 15) {
    float base = (j0 == 0) ? bo[0] : 0.0f;
#pragma unroll
    for (int r = 0; r < 4; ++r) {
      int rr = r0 + wv * 16 + ((l >> 4) << 2) + r;
      if (rr < RTOT) atomicAdd(&out[rr], part[r] + base);
    }
  }
}

// ---------------- launch ----------------
extern "C" void kernel_launch(void* const* d_in, const int* in_sizes, int n_in,
                              void* d_out, int out_size, void* d_ws, size_t ws_size,
                              hipStream_t stream) {
  const float* F     = (const float*)d_in[0];
  const float* text  = (const float*)d_in[1];
  const float* A     = (const float*)d_in[2];
  const float* gamma = (const float*)d_in[3];
  const float* beta  = (const float*)d_in[4];
  const float* Wh    = (const float*)d_in[5];
  const float* bh    = (const float*)d_in[6];
  const float* Wo    = (const float*)d_in[7];
  const float* bo    = (const float*)d_in[8];
  float* out = (float*)d_out;
  char* ws = (char*)d_ws;
  unsigned short* tAb = (unsigned short*)(ws + OFS_TAB);
  float* TB    = (float*)(ws + OFS_TB);
  float* stats = (float*)(ws + OFS_STATS);
  unsigned short* Whb = (unsigned short*)(ws + OFS_WHB);
  __half* sbuf = (__half*)(ws + OFS_S);
  unsigned short* s1b = (unsigned short*)(ws + OFS_S1B);
  unsigned short* f1b = (unsigned short*)(ws + OFS_F1);
  unsigned short* Fb  = (unsigned short*)(ws + OFS_FB);
  unsigned short* tHL = (unsigned short*)(ws + OFS_THL);
  unsigned short* aHL = (unsigned short*)(ws + OFS_AHL);
  unsigned short* wHL = (unsigned short*)(ws + OFS_WHL);
  ull* qpart = (ull*)(ws + OFS_QPART);

  k_pack<<<512, 256, 0, stream>>>(F, Wh, text, A, Fb, Whb, tHL, aHL, wHL,
                                  out, out_size, stats, (uint4*)qpart);
  k_pre<<<dim3(8, 5, 2), 256, 0, stream>>>(tHL, aHL, wHL, bh, tAb, TB);
  k_s<<<dim3(5, 7, 32), 256, 0, stream>>>(Fb, tAb, sbuf, stats);
  k_sinkhorn<<<dim3(BDIM, SBLK), 320, 0, stream>>>(sbuf, stats, gamma, beta, s1b, qpart);
  k_f1<<<dim3(8, 5, 32), 256, 0, stream>>>(s1b, Fb, f1b);
  k_hp<<<dim3(4, 158), 256, 0, stream>>>(f1b, Whb, TB, Wo, bo, out);
}